// Round 1
// baseline (2008.782 us; speedup 1.0000x reference)
//
#include <hip/hip_runtime.h>
#include <math.h>

#define NEGV -1e10f

__device__ __forceinline__ float fast_sig(float x) {
    return 1.0f / (1.0f + __expf(-x));
}
__device__ __forceinline__ float fast_tanh(float x) {
    float ax = fabsf(x);
    float e = __expf(2.0f * ax);
    float t = 1.0f - 2.0f / (e + 1.0f);
    return copysignf(t, x);
}

// ---------------- GEMM: C[M,N] = A[M,K] @ B[N,K]^T (+bias[N]) ----------------
__global__ __launch_bounds__(256) void gemm_bias_kernel(
    const float* __restrict__ A, const float* __restrict__ B,
    const float* __restrict__ bias, float* __restrict__ C,
    int M, int N, int K, int lda, int ldb, int ldc)
{
    __shared__ float As[16][68];
    __shared__ float Bs[16][68];
    const int tid = threadIdx.x;
    const int bm = blockIdx.y * 64;
    const int bn = blockIdx.x * 64;
    const int tx = tid & 15;
    const int ty = tid >> 4;
    const int lm = tid & 63;
    const int lk = (tid >> 6) << 2;   // 0,4,8,12
    float acc[4][4] = {};
    const int arow = bm + lm;
    const int brow = bn + lm;

    for (int k0 = 0; k0 < K; k0 += 16) {
        int k = k0 + lk;
        float4 av = make_float4(0.f, 0.f, 0.f, 0.f);
        float4 bv = make_float4(0.f, 0.f, 0.f, 0.f);
        if (arow < M) {
            if (k + 4 <= K) {
                av = *(const float4*)(A + (size_t)arow * lda + k);
            } else {
                float* p = (float*)&av;
                for (int i = 0; i < 4; i++) if (k + i < K) p[i] = A[(size_t)arow * lda + k + i];
            }
        }
        if (brow < N) {
            if (k + 4 <= K) {
                bv = *(const float4*)(B + (size_t)brow * ldb + k);
            } else {
                float* p = (float*)&bv;
                for (int i = 0; i < 4; i++) if (k + i < K) p[i] = B[(size_t)brow * ldb + k + i];
            }
        }
        As[lk + 0][lm] = av.x; As[lk + 1][lm] = av.y; As[lk + 2][lm] = av.z; As[lk + 3][lm] = av.w;
        Bs[lk + 0][lm] = bv.x; Bs[lk + 1][lm] = bv.y; Bs[lk + 2][lm] = bv.z; Bs[lk + 3][lm] = bv.w;
        __syncthreads();
        #pragma unroll
        for (int kk = 0; kk < 16; kk++) {
            float a[4], bb[4];
            #pragma unroll
            for (int i = 0; i < 4; i++) a[i] = As[kk][ty * 4 + i];
            #pragma unroll
            for (int j = 0; j < 4; j++) bb[j] = Bs[kk][tx * 4 + j];
            #pragma unroll
            for (int i = 0; i < 4; i++)
                #pragma unroll
                for (int j = 0; j < 4; j++)
                    acc[i][j] = fmaf(a[i], bb[j], acc[i][j]);
        }
        __syncthreads();
    }
    #pragma unroll
    for (int i = 0; i < 4; i++) {
        int row = bm + ty * 4 + i;
        if (row >= M) continue;
        #pragma unroll
        for (int j = 0; j < 4; j++) {
            int col = bn + tx * 4 + j;
            if (col < N) C[(size_t)row * ldc + col] = acc[i][j] + (bias ? bias[col] : 0.f);
        }
    }
}

// ---------------- LSTM scan: one block per (batch, direction) ----------------
// proj_* : [Bn, T, 256] precomputed x@Wih.T + b (on NON-reversed x).
// Backward dir handled via index t = L-1-s for both proj read and output write.
// Output: out[b, t, dir*64 + j] for j<64, rows t>=L zero-filled.
__global__ __launch_bounds__(256) void lstm_scan_kernel(
    const float* __restrict__ proj_f, const float* __restrict__ proj_b,
    const float* __restrict__ Whh_f, const float* __restrict__ Whh_b,
    const int* __restrict__ lengths,
    float* __restrict__ out, int T, int out_stride)
{
    const int b = blockIdx.x;
    const int dir = blockIdx.y;
    const float* proj = (dir ? proj_b : proj_f) + (size_t)b * T * 256;
    const float* Whh = dir ? Whh_b : Whh_f;
    const int L = lengths[b];
    const int j = threadIdx.x;

    float w[64];
    #pragma unroll
    for (int k = 0; k < 64; k++) w[k] = Whh[j * 64 + k];

    __shared__ float h_s[64];
    __shared__ float g_s[256];
    if (j < 64) h_s[j] = 0.f;
    float c = 0.f;
    __syncthreads();

    float* outb = out + (size_t)b * T * out_stride + dir * 64;
    for (int s = 0; s < L; s++) {
        const int t = dir ? (L - 1 - s) : s;
        float acc0 = 0.f, acc1 = 0.f, acc2 = 0.f, acc3 = 0.f;
        #pragma unroll
        for (int k = 0; k < 64; k += 4) {
            acc0 = fmaf(w[k + 0], h_s[k + 0], acc0);
            acc1 = fmaf(w[k + 1], h_s[k + 1], acc1);
            acc2 = fmaf(w[k + 2], h_s[k + 2], acc2);
            acc3 = fmaf(w[k + 3], h_s[k + 3], acc3);
        }
        g_s[j] = proj[(size_t)t * 256 + j] + ((acc0 + acc1) + (acc2 + acc3));
        __syncthreads();
        if (j < 64) {
            float ig = fast_sig(g_s[j]);
            float fg = fast_sig(g_s[64 + j]);
            float gg = fast_tanh(g_s[128 + j]);
            float og = fast_sig(g_s[192 + j]);
            c = fg * c + ig * gg;
            float hv = og * fast_tanh(c);
            h_s[j] = hv;
            outb[(size_t)t * out_stride + j] = hv;
        }
        __syncthreads();
    }
    // zero-fill masked region t in [L, T)
    for (int idx = j; idx < (T - L) * 64; idx += 256) {
        int t = L + (idx >> 6);
        outb[(size_t)t * out_stride + (idx & 63)] = 0.f;
    }
}

// ---------------- one-hot knowledge into wenc_n cols 128..139 ----------------
__global__ __launch_bounds__(256) void onehot_kernel(
    const int* __restrict__ knowledge, float* __restrict__ wenc_n)
{
    int idx = blockIdx.x * 256 + threadIdx.x;   // b*512 + t
    if (idx >= 96 * 512) return;
    int kn = knowledge[idx];
    float* row = wenc_n + (size_t)idx * 140 + 128;
    #pragma unroll
    for (int q = 0; q < 12; q++) row[q] = (q == kn) ? 1.f : 0.f;
}

// ---------------- header: pick last valid step + one-hot ----------------
__global__ __launch_bounds__(256) void build_hs_kernel(
    const float* __restrict__ h1_head, const int* __restrict__ l_hpu,
    const int* __restrict__ knowledge_header, float* __restrict__ wenc_hs)
{
    int b = blockIdx.x, u = blockIdx.y;
    int g = b * 16 + u;
    int tid = threadIdx.x;
    int L = l_hpu[g];
    if (tid < 128) {
        wenc_hs[(size_t)g * 132 + tid] = h1_head[((size_t)g * 8 + (L - 1)) * 128 + tid];
    } else if (tid < 132) {
        int kh = knowledge_header[g];
        wenc_hs[(size_t)g * 132 + tid] = ((tid - 128) == kh) ? 1.f : 0.f;
    }
}

__global__ __launch_bounds__(256) void build_hsob_kernel(
    const float* __restrict__ wenc_hs, const int* __restrict__ wc,
    const int* __restrict__ wn, float* __restrict__ hs_ob)
{
    int b = blockIdx.x, w = blockIdx.y;
    int tid = threadIdx.x;
    int col = (w < wn[b]) ? wc[b * 4 + w] : 0;
    if (tid < 132)
        hs_ob[((size_t)b * 4 + w)* 132 + tid] = wenc_hs[((size_t)b * 16 + col) * 132 + tid];
}

// ---------------- attention scores + softmax + context (per (b,w)) ----------------
__global__ __launch_bounds__(256) void att_softmax_cn_kernel(
    const float* __restrict__ attx, const float* __restrict__ hs_ob,
    const float* __restrict__ wenc_n, const int* __restrict__ l_n,
    float* __restrict__ c_n)
{
    int b = blockIdx.x, w = blockIdx.y;
    int tid = threadIdx.x;
    int L = l_n[b];
    __shared__ float q[132];
    __shared__ float sc[512];
    __shared__ float red[256];
    if (tid < 132) q[tid] = hs_ob[((size_t)b * 4 + w) * 132 + tid];
    __syncthreads();
    for (int t = tid; t < 512; t += 256) {
        float s = -1e30f;
        if (t < L) {
            const float* ax = attx + ((size_t)b * 512 + t) * 132;
            float s0 = 0.f, s1 = 0.f, s2 = 0.f, s3 = 0.f;
            #pragma unroll
            for (int d = 0; d < 132; d += 4) {
                s0 = fmaf(ax[d + 0], q[d + 0], s0);
                s1 = fmaf(ax[d + 1], q[d + 1], s1);
                s2 = fmaf(ax[d + 2], q[d + 2], s2);
                s3 = fmaf(ax[d + 3], q[d + 3], s3);
            }
            s = (s0 + s1) + (s2 + s3);
        }
        sc[t] = s;
    }
    __syncthreads();
    red[tid] = fmaxf(sc[tid], sc[tid + 256]);
    __syncthreads();
    for (int off = 128; off > 0; off >>= 1) {
        if (tid < off) red[tid] = fmaxf(red[tid], red[tid + off]);
        __syncthreads();
    }
    float m = red[0];
    __syncthreads();
    float ps = 0.f;
    for (int t = tid; t < 512; t += 256) {
        float e = (t < L) ? __expf(sc[t] - m) : 0.f;
        sc[t] = e;
        ps += e;
    }
    red[tid] = ps;
    __syncthreads();
    for (int off = 128; off > 0; off >>= 1) {
        if (tid < off) red[tid] += red[tid + off];
        __syncthreads();
    }
    float inv = 1.f / red[0];
    if (tid < 140) {
        float acc = 0.f;
        for (int t = 0; t < L; t++)
            acc = fmaf(sc[t], wenc_n[((size_t)b * 512 + t) * 140 + tid], acc);
        c_n[((size_t)b * 4 + w) * 140 + tid] = acc * inv;
    }
}

// ---------------- vec = [c_n@Wc.T+b | hs_ob@Whs.T+b | Wop[:,op]+b] ----------------
__global__ __launch_bounds__(384) void build_vec_kernel(
    const float* __restrict__ c_n, const float* __restrict__ hs_ob,
    const float* __restrict__ Wc_w, const float* __restrict__ Wc_b,
    const float* __restrict__ Whs_w, const float* __restrict__ Whs_b,
    const float* __restrict__ Wop_w, const float* __restrict__ Wop_b,
    const int* __restrict__ wn, const int* __restrict__ wo,
    float* __restrict__ vec)
{
    int b = blockIdx.x, w = blockIdx.y;
    int j = threadIdx.x;
    __shared__ float cn[140];
    __shared__ float hb[132];
    if (j < 140) cn[j] = c_n[((size_t)b * 4 + w) * 140 + j];
    else if (j < 272) hb[j - 140] = hs_ob[((size_t)b * 4 + w) * 132 + (j - 140)];
    __syncthreads();
    float acc;
    if (j < 128) {
        acc = Wc_b[j];
        const float* r = Wc_w + (size_t)j * 140;
        for (int d = 0; d < 140; d++) acc = fmaf(r[d], cn[d], acc);
    } else if (j < 256) {
        int jj = j - 128;
        acc = Whs_b[jj];
        const float* r = Whs_w + (size_t)jj * 132;
        for (int d = 0; d < 132; d++) acc = fmaf(r[d], hb[d], acc);
    } else {
        int jj = j - 256;
        int op = (w < wn[b]) ? wo[b * 4 + w] : 0;
        acc = Wop_b[jj] + Wop_w[jj * 4 + op];
    }
    vec[((size_t)b * 4 + w) * 384 + j] = acc;
}

// ---------------- final: out[b,w,t,:] = tanh(vpart+npart)@out2.T + b, masked ----------------
__global__ __launch_bounds__(256) void final_kernel(
    const float* __restrict__ vpart, const float* __restrict__ npart,
    const float* __restrict__ out2_w, const float* __restrict__ out2_b,
    const int* __restrict__ l_n, float* __restrict__ out)
{
    int b = blockIdx.y;
    int tid = threadIdx.x;
    int t = blockIdx.x * 256 + tid;
    __shared__ float vp[512];
    __shared__ float w2[256];
    w2[tid] = out2_w[tid];
    for (int i = tid; i < 512; i += 256) vp[i] = vpart[(size_t)b * 512 + i];
    __syncthreads();
    int L = l_n[b];
    float s[4][2];
    if (t < L) {
        float b0 = out2_b[0], b1 = out2_b[1];
        #pragma unroll
        for (int w = 0; w < 4; w++) { s[w][0] = b0; s[w][1] = b1; }
        const float4* np4 = (const float4*)(npart + ((size_t)b * 512 + t) * 128);
        for (int h4 = 0; h4 < 32; h4++) {
            float4 n = np4[h4];
            const float* nf = (const float*)&n;
            #pragma unroll
            for (int e = 0; e < 4; e++) {
                int h = h4 * 4 + e;
                float nv = nf[e];
                float w0 = w2[h], w1 = w2[128 + h];
                #pragma unroll
                for (int w = 0; w < 4; w++) {
                    float z = fast_tanh(vp[w * 128 + h] + nv);
                    s[w][0] = fmaf(z, w0, s[w][0]);
                    s[w][1] = fmaf(z, w1, s[w][1]);
                }
            }
        }
    } else {
        #pragma unroll
        for (int w = 0; w < 4; w++) { s[w][0] = NEGV; s[w][1] = NEGV; }
    }
    #pragma unroll
    for (int w = 0; w < 4; w++) {
        size_t o = (((size_t)b * 4 + w) * 512 + t) * 2;
        out[o + 0] = s[w][0];
        out[o + 1] = s[w][1];
    }
}

// ---------------------------------------------------------------------------
extern "C" void kernel_launch(void* const* d_in, const int* in_sizes, int n_in,
                              void* d_out, int out_size, void* d_ws, size_t ws_size,
                              hipStream_t stream)
{
    const float* wemb_n   = (const float*)d_in[0];
    const float* wemb_hpu = (const float*)d_in[1];
    const float* Wih_n0f = (const float*)d_in[2];
    const float* Whh_n0f = (const float*)d_in[3];
    const float* b_n0f   = (const float*)d_in[4];
    const float* Wih_n0b = (const float*)d_in[5];
    const float* Whh_n0b = (const float*)d_in[6];
    const float* b_n0b   = (const float*)d_in[7];
    const float* Wih_n1f = (const float*)d_in[8];
    const float* Whh_n1f = (const float*)d_in[9];
    const float* b_n1f   = (const float*)d_in[10];
    const float* Wih_n1b = (const float*)d_in[11];
    const float* Whh_n1b = (const float*)d_in[12];
    const float* b_n1b   = (const float*)d_in[13];
    const float* Wih_h0f = (const float*)d_in[14];
    const float* Whh_h0f = (const float*)d_in[15];
    const float* b_h0f   = (const float*)d_in[16];
    const float* Wih_h0b = (const float*)d_in[17];
    const float* Whh_h0b = (const float*)d_in[18];
    const float* b_h0b   = (const float*)d_in[19];
    const float* Wih_h1f = (const float*)d_in[20];
    const float* Whh_h1f = (const float*)d_in[21];
    const float* b_h1f   = (const float*)d_in[22];
    const float* Wih_h1b = (const float*)d_in[23];
    const float* Whh_h1b = (const float*)d_in[24];
    const float* b_h1b   = (const float*)d_in[25];
    const float* Watt_w  = (const float*)d_in[26];
    const float* Watt_b  = (const float*)d_in[27];
    const float* Wc_w    = (const float*)d_in[28];
    const float* Wc_b    = (const float*)d_in[29];
    const float* Whs_w   = (const float*)d_in[30];
    const float* Whs_b   = (const float*)d_in[31];
    const float* Wop_w   = (const float*)d_in[32];
    const float* Wop_b   = (const float*)d_in[33];
    const float* out1_w  = (const float*)d_in[34];
    const float* out1_b  = (const float*)d_in[35];
    const float* out2_w  = (const float*)d_in[36];
    const float* out2_b  = (const float*)d_in[37];
    const int* l_n   = (const int*)d_in[38];
    const int* l_hpu = (const int*)d_in[39];
    const int* wc    = (const int*)d_in[40];
    const int* wn    = (const int*)d_in[41];
    const int* wo    = (const int*)d_in[42];
    const int* knowledge        = (const int*)d_in[43];
    const int* knowledge_header = (const int*)d_in[44];

    float* ws = (float*)d_ws;
    // workspace layout (floats); projA region reused for attx/npart after header
    float* proj_f  = ws + 0;           // 12,582,912
    float* proj_b  = ws + 12582912;    // 12,582,912
    float* wenc0   = ws + 25165824;    // 6,291,456  (question L0 out; header h0 reuses)
    float* h_h0    = ws + 25165824;    // 1,572,864
    float* h1_head = ws + 26738688;    // 1,572,864
    float* wenc_n  = ws + 31457280;    // 6,881,280  [96,512,140]
    float* attx    = ws + 0;           // 6,488,064  (reuse proj area, after header done)
    float* npart   = ws + 6488064;     // 6,291,456  (reuse proj area)
    float* wenc_hs = ws + 38338560;    // 202,752
    float* hs_ob   = ws + 38541312;    // 50,688
    float* c_n     = ws + 38592000;    // 53,760
    float* vec     = ws + 38645760;    // 147,456
    float* vpart   = ws + 38793216;    // 49,152
    float* outp    = (float*)d_out;

    dim3 blk(256);
    auto gemm = [&](const float* A, const float* B, const float* bias, float* C,
                    int M, int N, int K, int lda, int ldb, int ldc) {
        dim3 grid((N + 63) / 64, (M + 63) / 64);
        gemm_bias_kernel<<<grid, blk, 0, stream>>>(A, B, bias, C, M, N, K, lda, ldb, ldc);
    };

    // ---- question encoder, layer 0 (input 512) ----
    gemm(wemb_n, Wih_n0f, b_n0f, proj_f, 96 * 512, 256, 512, 512, 512, 256);
    gemm(wemb_n, Wih_n0b, b_n0b, proj_b, 96 * 512, 256, 512, 512, 512, 256);
    lstm_scan_kernel<<<dim3(96, 2), blk, 0, stream>>>(proj_f, proj_b, Whh_n0f, Whh_n0b,
                                                      l_n, wenc0, 512, 128);
    // ---- question encoder, layer 1 (input 128) ----
    gemm(wenc0, Wih_n1f, b_n1f, proj_f, 96 * 512, 256, 128, 128, 128, 256);
    gemm(wenc0, Wih_n1b, b_n1b, proj_b, 96 * 512, 256, 128, 128, 128, 256);
    lstm_scan_kernel<<<dim3(96, 2), blk, 0, stream>>>(proj_f, proj_b, Whh_n1f, Whh_n1b,
                                                      l_n, wenc_n, 512, 140);
    onehot_kernel<<<dim3(192), blk, 0, stream>>>(knowledge, wenc_n);

    // ---- header encoder, layer 0 ----
    gemm(wemb_hpu, Wih_h0f, b_h0f, proj_f, 1536 * 8, 256, 512, 512, 512, 256);
    gemm(wemb_hpu, Wih_h0b, b_h0b, proj_b, 1536 * 8, 256, 512, 512, 512, 256);
    lstm_scan_kernel<<<dim3(1536, 2), blk, 0, stream>>>(proj_f, proj_b, Whh_h0f, Whh_h0b,
                                                        l_hpu, h_h0, 8, 128);
    // ---- header encoder, layer 1 ----
    gemm(h_h0, Wih_h1f, b_h1f, proj_f, 1536 * 8, 256, 128, 128, 128, 256);
    gemm(h_h0, Wih_h1b, b_h1b, proj_b, 1536 * 8, 256, 128, 128, 128, 256);
    lstm_scan_kernel<<<dim3(1536, 2), blk, 0, stream>>>(proj_f, proj_b, Whh_h1f, Whh_h1b,
                                                        l_hpu, h1_head, 8, 128);
    build_hs_kernel<<<dim3(96, 16), blk, 0, stream>>>(h1_head, l_hpu, knowledge_header, wenc_hs);
    build_hsob_kernel<<<dim3(96, 4), blk, 0, stream>>>(wenc_hs, wc, wn, hs_ob);

    // ---- attention ----
    gemm(wenc_n, Watt_w, Watt_b, attx, 96 * 512, 132, 140, 140, 140, 132);
    att_softmax_cn_kernel<<<dim3(96, 4), blk, 0, stream>>>(attx, hs_ob, wenc_n, l_n, c_n);

    // ---- vec / split out1 ----
    build_vec_kernel<<<dim3(96, 4), dim3(384), 0, stream>>>(c_n, hs_ob, Wc_w, Wc_b,
                                                            Whs_w, Whs_b, Wop_w, Wop_b,
                                                            wn, wo, vec);
    gemm(vec, out1_w, out1_b, vpart, 96 * 4, 128, 384, 384, 524, 128);
    gemm(wenc_n, out1_w + 384, nullptr, npart, 96 * 512, 128, 140, 140, 524, 128);

    // ---- final ----
    final_kernel<<<dim3(2, 96), blk, 0, stream>>>(vpart, npart, out2_w, out2_b, l_n, outp);
}

// Round 2
// 1927.756 us; speedup vs baseline: 1.0420x; 1.0420x over previous
//
#include <hip/hip_runtime.h>
#include <math.h>

#define NEGV -1e10f

__device__ __forceinline__ float fast_sig(float x) {
    return 1.0f / (1.0f + __expf(-x));
}
__device__ __forceinline__ float fast_tanh(float x) {
    float ax = fabsf(x);
    float e = __expf(2.0f * ax);
    float t = 1.0f - 2.0f / (e + 1.0f);
    return copysignf(t, x);
}

// ---------------- GEMM: C[M,N] = A[M,K] @ B[N,K]^T (+bias[N]) ----------------
__global__ __launch_bounds__(256) void gemm_bias_kernel(
    const float* __restrict__ A, const float* __restrict__ B,
    const float* __restrict__ bias, float* __restrict__ C,
    int M, int N, int K, int lda, int ldb, int ldc)
{
    __shared__ float As[16][68];
    __shared__ float Bs[16][68];
    const int tid = threadIdx.x;
    const int bm = blockIdx.y * 64;
    const int bn = blockIdx.x * 64;
    const int tx = tid & 15;
    const int ty = tid >> 4;
    const int lm = tid & 63;
    const int lk = (tid >> 6) << 2;   // 0,4,8,12
    float acc[4][4] = {};
    const int arow = bm + lm;
    const int brow = bn + lm;

    for (int k0 = 0; k0 < K; k0 += 16) {
        int k = k0 + lk;
        float4 av = make_float4(0.f, 0.f, 0.f, 0.f);
        float4 bv = make_float4(0.f, 0.f, 0.f, 0.f);
        if (arow < M) {
            if (k + 4 <= K) {
                av = *(const float4*)(A + (size_t)arow * lda + k);
            } else {
                float* p = (float*)&av;
                for (int i = 0; i < 4; i++) if (k + i < K) p[i] = A[(size_t)arow * lda + k + i];
            }
        }
        if (brow < N) {
            if (k + 4 <= K) {
                bv = *(const float4*)(B + (size_t)brow * ldb + k);
            } else {
                float* p = (float*)&bv;
                for (int i = 0; i < 4; i++) if (k + i < K) p[i] = B[(size_t)brow * ldb + k + i];
            }
        }
        As[lk + 0][lm] = av.x; As[lk + 1][lm] = av.y; As[lk + 2][lm] = av.z; As[lk + 3][lm] = av.w;
        Bs[lk + 0][lm] = bv.x; Bs[lk + 1][lm] = bv.y; Bs[lk + 2][lm] = bv.z; Bs[lk + 3][lm] = bv.w;
        __syncthreads();
        #pragma unroll
        for (int kk = 0; kk < 16; kk++) {
            float a[4], bb[4];
            #pragma unroll
            for (int i = 0; i < 4; i++) a[i] = As[kk][ty * 4 + i];
            #pragma unroll
            for (int j = 0; j < 4; j++) bb[j] = Bs[kk][tx * 4 + j];
            #pragma unroll
            for (int i = 0; i < 4; i++)
                #pragma unroll
                for (int j = 0; j < 4; j++)
                    acc[i][j] = fmaf(a[i], bb[j], acc[i][j]);
        }
        __syncthreads();
    }
    #pragma unroll
    for (int i = 0; i < 4; i++) {
        int row = bm + ty * 4 + i;
        if (row >= M) continue;
        #pragma unroll
        for (int j = 0; j < 4; j++) {
            int col = bn + tx * 4 + j;
            if (col < N) C[(size_t)row * ldc + col] = acc[i][j] + (bias ? bias[col] : 0.f);
        }
    }
}

// ---------------- LSTM scan: one block per (batch, direction) ----------------
// proj_* : [Bn, T, 256] precomputed x@Wih.T + b (gate-major rows: i,f,g,o).
// Structure: 4 waves; wave w owns units 16w..16w+15. lane = gate*16 + u_local.
// h broadcast: 1 ds_read_b32 per lane + v_readlane (SGPR) per k. One barrier
// per step via double-buffered h_s. proj row prefetched one step ahead.
__global__ __launch_bounds__(256) void lstm_scan_kernel(
    const float* __restrict__ proj_f, const float* __restrict__ proj_b,
    const float* __restrict__ Whh_f, const float* __restrict__ Whh_b,
    const int* __restrict__ lengths,
    float* __restrict__ out, int T, int out_stride)
{
    const int b = blockIdx.x;
    const int dir = blockIdx.y;
    const float* proj = (dir ? proj_b : proj_f) + (size_t)b * T * 256;
    const float* Whh = dir ? Whh_b : Whh_f;
    const int L = lengths[b];
    const int tid = threadIdx.x;
    const int wv = tid >> 6;                 // wave 0..3
    const int lane = tid & 63;
    const int g = lane >> 4;                 // gate: 0=i 1=f 2=g 3=o
    const int u = (wv << 4) + (lane & 15);   // unit 0..63
    const int row = (g << 6) + u;            // row in Whh / proj

    // gate weights in registers (64 floats as 16 float4 -> static indexing)
    float4 w4[16];
    #pragma unroll
    for (int k4 = 0; k4 < 16; k4++)
        w4[k4] = *(const float4*)(Whh + (size_t)row * 64 + k4 * 4);

    const bool isg = (g == 2);
    const float escale = isg ? -2.f : -1.f;  // tanh uses exp(-2x), sig exp(-x)
    const float vmul   = isg ?  2.f :  1.f;  // tanh = 2*r-1, sig = r
    const float vadd   = isg ? -1.f :  0.f;

    __shared__ float h_s[2][64];
    if (tid < 64) h_s[0][tid] = 0.f;
    __syncthreads();

    float c = 0.f;
    float* outb = out + (size_t)b * T * out_stride + dir * 64;

    const int t0 = dir ? (L - 1) : 0;
    float p_cur = proj[(size_t)t0 * 256 + row];

    for (int s = 0; s < L; s++) {
        const int cur = s & 1;
        const int nxt = cur ^ 1;
        // prefetch next step's proj row (hides HBM/L2 latency under matvec)
        float p_next = 0.f;
        if (s + 1 < L) {
            const int tn = dir ? (L - 2 - s) : (s + 1);
            p_next = proj[(size_t)tn * 256 + row];
        }

        const int hbits = __float_as_int(h_s[cur][lane]);
        float acc0 = p_cur, acc1 = 0.f, acc2 = 0.f, acc3 = 0.f;
        #pragma unroll
        for (int k4 = 0; k4 < 16; k4++) {
            const float4 wk = w4[k4];
            acc0 = fmaf(wk.x, __int_as_float(__builtin_amdgcn_readlane(hbits, 4 * k4 + 0)), acc0);
            acc1 = fmaf(wk.y, __int_as_float(__builtin_amdgcn_readlane(hbits, 4 * k4 + 1)), acc1);
            acc2 = fmaf(wk.z, __int_as_float(__builtin_amdgcn_readlane(hbits, 4 * k4 + 2)), acc2);
            acc3 = fmaf(wk.w, __int_as_float(__builtin_amdgcn_readlane(hbits, 4 * k4 + 3)), acc3);
        }
        const float x = (acc0 + acc1) + (acc2 + acc3);
        const float e = __expf(x * escale);
        const float r = __builtin_amdgcn_rcpf(1.f + e);
        const float val = fmaf(vmul, r, vadd);   // sig(x) or tanh(x) per gate

        const float fv = __shfl_xor(val, 16);    // f-gate (lanes 16..31)
        const float gv = __shfl_xor(val, 32);    // g-gate (lanes 32..47)
        const float ov = __shfl_xor(val, 48);    // o-gate (lanes 48..63)

        if (lane < 16) {                          // these lanes hold i-gate
            c = fmaf(fv, c, val * gv);
            const float e2 = __expf(-2.f * c);
            const float th = fmaf(2.f, __builtin_amdgcn_rcpf(1.f + e2), -1.f);
            const float hv = ov * th;
            const int t = dir ? (L - 1 - s) : s;
            h_s[nxt][u] = hv;
            outb[(size_t)t * out_stride + u] = hv;
        }
        p_cur = p_next;
        __syncthreads();
    }
    // zero-fill masked region t in [L, T)
    for (int idx = tid; idx < (T - L) * 64; idx += 256) {
        int t = L + (idx >> 6);
        outb[(size_t)t * out_stride + (idx & 63)] = 0.f;
    }
}

// ---------------- one-hot knowledge into wenc_n cols 128..139 ----------------
__global__ __launch_bounds__(256) void onehot_kernel(
    const int* __restrict__ knowledge, float* __restrict__ wenc_n)
{
    int idx = blockIdx.x * 256 + threadIdx.x;   // b*512 + t
    if (idx >= 96 * 512) return;
    int kn = knowledge[idx];
    float* row = wenc_n + (size_t)idx * 140 + 128;
    #pragma unroll
    for (int q = 0; q < 12; q++) row[q] = (q == kn) ? 1.f : 0.f;
}

// ---------------- header: pick last valid step + one-hot ----------------
__global__ __launch_bounds__(256) void build_hs_kernel(
    const float* __restrict__ h1_head, const int* __restrict__ l_hpu,
    const int* __restrict__ knowledge_header, float* __restrict__ wenc_hs)
{
    int b = blockIdx.x, u = blockIdx.y;
    int g = b * 16 + u;
    int tid = threadIdx.x;
    int L = l_hpu[g];
    if (tid < 128) {
        wenc_hs[(size_t)g * 132 + tid] = h1_head[((size_t)g * 8 + (L - 1)) * 128 + tid];
    } else if (tid < 132) {
        int kh = knowledge_header[g];
        wenc_hs[(size_t)g * 132 + tid] = ((tid - 128) == kh) ? 1.f : 0.f;
    }
}

__global__ __launch_bounds__(256) void build_hsob_kernel(
    const float* __restrict__ wenc_hs, const int* __restrict__ wc,
    const int* __restrict__ wn, float* __restrict__ hs_ob)
{
    int b = blockIdx.x, w = blockIdx.y;
    int tid = threadIdx.x;
    int col = (w < wn[b]) ? wc[b * 4 + w] : 0;
    if (tid < 132)
        hs_ob[((size_t)b * 4 + w)* 132 + tid] = wenc_hs[((size_t)b * 16 + col) * 132 + tid];
}

// ---------------- attention scores + softmax + context (per (b,w)) ----------------
__global__ __launch_bounds__(256) void att_softmax_cn_kernel(
    const float* __restrict__ attx, const float* __restrict__ hs_ob,
    const float* __restrict__ wenc_n, const int* __restrict__ l_n,
    float* __restrict__ c_n)
{
    int b = blockIdx.x, w = blockIdx.y;
    int tid = threadIdx.x;
    int L = l_n[b];
    __shared__ float q[132];
    __shared__ float sc[512];
    __shared__ float red[256];
    if (tid < 132) q[tid] = hs_ob[((size_t)b * 4 + w) * 132 + tid];
    __syncthreads();
    for (int t = tid; t < 512; t += 256) {
        float s = -1e30f;
        if (t < L) {
            const float* ax = attx + ((size_t)b * 512 + t) * 132;
            float s0 = 0.f, s1 = 0.f, s2 = 0.f, s3 = 0.f;
            #pragma unroll
            for (int d = 0; d < 132; d += 4) {
                s0 = fmaf(ax[d + 0], q[d + 0], s0);
                s1 = fmaf(ax[d + 1], q[d + 1], s1);
                s2 = fmaf(ax[d + 2], q[d + 2], s2);
                s3 = fmaf(ax[d + 3], q[d + 3], s3);
            }
            s = (s0 + s1) + (s2 + s3);
        }
        sc[t] = s;
    }
    __syncthreads();
    red[tid] = fmaxf(sc[tid], sc[tid + 256]);
    __syncthreads();
    for (int off = 128; off > 0; off >>= 1) {
        if (tid < off) red[tid] = fmaxf(red[tid], red[tid + off]);
        __syncthreads();
    }
    float m = red[0];
    __syncthreads();
    float ps = 0.f;
    for (int t = tid; t < 512; t += 256) {
        float e = (t < L) ? __expf(sc[t] - m) : 0.f;
        sc[t] = e;
        ps += e;
    }
    red[tid] = ps;
    __syncthreads();
    for (int off = 128; off > 0; off >>= 1) {
        if (tid < off) red[tid] += red[tid + off];
        __syncthreads();
    }
    float inv = 1.f / red[0];
    if (tid < 140) {
        float acc = 0.f;
        for (int t = 0; t < L; t++)
            acc = fmaf(sc[t], wenc_n[((size_t)b * 512 + t) * 140 + tid], acc);
        c_n[((size_t)b * 4 + w) * 140 + tid] = acc * inv;
    }
}

// ---------------- vec = [c_n@Wc.T+b | hs_ob@Whs.T+b | Wop[:,op]+b] ----------------
__global__ __launch_bounds__(384) void build_vec_kernel(
    const float* __restrict__ c_n, const float* __restrict__ hs_ob,
    const float* __restrict__ Wc_w, const float* __restrict__ Wc_b,
    const float* __restrict__ Whs_w, const float* __restrict__ Whs_b,
    const float* __restrict__ Wop_w, const float* __restrict__ Wop_b,
    const int* __restrict__ wn, const int* __restrict__ wo,
    float* __restrict__ vec)
{
    int b = blockIdx.x, w = blockIdx.y;
    int j = threadIdx.x;
    __shared__ float cn[140];
    __shared__ float hb[132];
    if (j < 140) cn[j] = c_n[((size_t)b * 4 + w) * 140 + j];
    else if (j < 272) hb[j - 140] = hs_ob[((size_t)b * 4 + w) * 132 + (j - 140)];
    __syncthreads();
    float acc;
    if (j < 128) {
        acc = Wc_b[j];
        const float* r = Wc_w + (size_t)j * 140;
        for (int d = 0; d < 140; d++) acc = fmaf(r[d], cn[d], acc);
    } else if (j < 256) {
        int jj = j - 128;
        acc = Whs_b[jj];
        const float* r = Whs_w + (size_t)jj * 132;
        for (int d = 0; d < 132; d++) acc = fmaf(r[d], hb[d], acc);
    } else {
        int jj = j - 256;
        int op = (w < wn[b]) ? wo[b * 4 + w] : 0;
        acc = Wop_b[jj] + Wop_w[jj * 4 + op];
    }
    vec[((size_t)b * 4 + w) * 384 + j] = acc;
}

// ---------------- final: out[b,w,t,:] = tanh(vpart+npart)@out2.T + b, masked ----------------
__global__ __launch_bounds__(256) void final_kernel(
    const float* __restrict__ vpart, const float* __restrict__ npart,
    const float* __restrict__ out2_w, const float* __restrict__ out2_b,
    const int* __restrict__ l_n, float* __restrict__ out)
{
    int b = blockIdx.y;
    int tid = threadIdx.x;
    int t = blockIdx.x * 256 + tid;
    __shared__ float vp[512];
    __shared__ float w2[256];
    w2[tid] = out2_w[tid];
    for (int i = tid; i < 512; i += 256) vp[i] = vpart[(size_t)b * 512 + i];
    __syncthreads();
    int L = l_n[b];
    float s[4][2];
    if (t < L) {
        float b0 = out2_b[0], b1 = out2_b[1];
        #pragma unroll
        for (int w = 0; w < 4; w++) { s[w][0] = b0; s[w][1] = b1; }
        const float4* np4 = (const float4*)(npart + ((size_t)b * 512 + t) * 128);
        for (int h4 = 0; h4 < 32; h4++) {
            float4 n = np4[h4];
            const float* nf = (const float*)&n;
            #pragma unroll
            for (int e = 0; e < 4; e++) {
                int h = h4 * 4 + e;
                float nv = nf[e];
                float w0 = w2[h], w1 = w2[128 + h];
                #pragma unroll
                for (int w = 0; w < 4; w++) {
                    float z = fast_tanh(vp[w * 128 + h] + nv);
                    s[w][0] = fmaf(z, w0, s[w][0]);
                    s[w][1] = fmaf(z, w1, s[w][1]);
                }
            }
        }
    } else {
        #pragma unroll
        for (int w = 0; w < 4; w++) { s[w][0] = NEGV; s[w][1] = NEGV; }
    }
    #pragma unroll
    for (int w = 0; w < 4; w++) {
        size_t o = (((size_t)b * 4 + w) * 512 + t) * 2;
        out[o + 0] = s[w][0];
        out[o + 1] = s[w][1];
    }
}

// ---------------------------------------------------------------------------
extern "C" void kernel_launch(void* const* d_in, const int* in_sizes, int n_in,
                              void* d_out, int out_size, void* d_ws, size_t ws_size,
                              hipStream_t stream)
{
    const float* wemb_n   = (const float*)d_in[0];
    const float* wemb_hpu = (const float*)d_in[1];
    const float* Wih_n0f = (const float*)d_in[2];
    const float* Whh_n0f = (const float*)d_in[3];
    const float* b_n0f   = (const float*)d_in[4];
    const float* Wih_n0b = (const float*)d_in[5];
    const float* Whh_n0b = (const float*)d_in[6];
    const float* b_n0b   = (const float*)d_in[7];
    const float* Wih_n1f = (const float*)d_in[8];
    const float* Whh_n1f = (const float*)d_in[9];
    const float* b_n1f   = (const float*)d_in[10];
    const float* Wih_n1b = (const float*)d_in[11];
    const float* Whh_n1b = (const float*)d_in[12];
    const float* b_n1b   = (const float*)d_in[13];
    const float* Wih_h0f = (const float*)d_in[14];
    const float* Whh_h0f = (const float*)d_in[15];
    const float* b_h0f   = (const float*)d_in[16];
    const float* Wih_h0b = (const float*)d_in[17];
    const float* Whh_h0b = (const float*)d_in[18];
    const float* b_h0b   = (const float*)d_in[19];
    const float* Wih_h1f = (const float*)d_in[20];
    const float* Whh_h1f = (const float*)d_in[21];
    const float* b_h1f   = (const float*)d_in[22];
    const float* Wih_h1b = (const float*)d_in[23];
    const float* Whh_h1b = (const float*)d_in[24];
    const float* b_h1b   = (const float*)d_in[25];
    const float* Watt_w  = (const float*)d_in[26];
    const float* Watt_b  = (const float*)d_in[27];
    const float* Wc_w    = (const float*)d_in[28];
    const float* Wc_b    = (const float*)d_in[29];
    const float* Whs_w   = (const float*)d_in[30];
    const float* Whs_b   = (const float*)d_in[31];
    const float* Wop_w   = (const float*)d_in[32];
    const float* Wop_b   = (const float*)d_in[33];
    const float* out1_w  = (const float*)d_in[34];
    const float* out1_b  = (const float*)d_in[35];
    const float* out2_w  = (const float*)d_in[36];
    const float* out2_b  = (const float*)d_in[37];
    const int* l_n   = (const int*)d_in[38];
    const int* l_hpu = (const int*)d_in[39];
    const int* wc    = (const int*)d_in[40];
    const int* wn    = (const int*)d_in[41];
    const int* wo    = (const int*)d_in[42];
    const int* knowledge        = (const int*)d_in[43];
    const int* knowledge_header = (const int*)d_in[44];

    float* ws = (float*)d_ws;
    // workspace layout (floats); projA region reused for attx/npart after header
    float* proj_f  = ws + 0;           // 12,582,912
    float* proj_b  = ws + 12582912;    // 12,582,912
    float* wenc0   = ws + 25165824;    // 6,291,456  (question L0 out; header h0 reuses)
    float* h_h0    = ws + 25165824;    // 1,572,864
    float* h1_head = ws + 26738688;    // 1,572,864
    float* wenc_n  = ws + 31457280;    // 6,881,280  [96,512,140]
    float* attx    = ws + 0;           // 6,488,064  (reuse proj area, after header done)
    float* npart   = ws + 6488064;     // 6,291,456  (reuse proj area)
    float* wenc_hs = ws + 38338560;    // 202,752
    float* hs_ob   = ws + 38541312;    // 50,688
    float* c_n     = ws + 38592000;    // 53,760
    float* vec     = ws + 38645760;    // 147,456
    float* vpart   = ws + 38793216;    // 49,152
    float* outp    = (float*)d_out;

    dim3 blk(256);
    auto gemm = [&](const float* A, const float* B, const float* bias, float* C,
                    int M, int N, int K, int lda, int ldb, int ldc) {
        dim3 grid((N + 63) / 64, (M + 63) / 64);
        gemm_bias_kernel<<<grid, blk, 0, stream>>>(A, B, bias, C, M, N, K, lda, ldb, ldc);
    };

    // ---- question encoder, layer 0 (input 512) ----
    gemm(wemb_n, Wih_n0f, b_n0f, proj_f, 96 * 512, 256, 512, 512, 512, 256);
    gemm(wemb_n, Wih_n0b, b_n0b, proj_b, 96 * 512, 256, 512, 512, 512, 256);
    lstm_scan_kernel<<<dim3(96, 2), blk, 0, stream>>>(proj_f, proj_b, Whh_n0f, Whh_n0b,
                                                      l_n, wenc0, 512, 128);
    // ---- question encoder, layer 1 (input 128) ----
    gemm(wenc0, Wih_n1f, b_n1f, proj_f, 96 * 512, 256, 128, 128, 128, 256);
    gemm(wenc0, Wih_n1b, b_n1b, proj_b, 96 * 512, 256, 128, 128, 128, 256);
    lstm_scan_kernel<<<dim3(96, 2), blk, 0, stream>>>(proj_f, proj_b, Whh_n1f, Whh_n1b,
                                                      l_n, wenc_n, 512, 140);
    onehot_kernel<<<dim3(192), blk, 0, stream>>>(knowledge, wenc_n);

    // ---- header encoder, layer 0 ----
    gemm(wemb_hpu, Wih_h0f, b_h0f, proj_f, 1536 * 8, 256, 512, 512, 512, 256);
    gemm(wemb_hpu, Wih_h0b, b_h0b, proj_b, 1536 * 8, 256, 512, 512, 512, 256);
    lstm_scan_kernel<<<dim3(1536, 2), blk, 0, stream>>>(proj_f, proj_b, Whh_h0f, Whh_h0b,
                                                        l_hpu, h_h0, 8, 128);
    // ---- header encoder, layer 1 ----
    gemm(h_h0, Wih_h1f, b_h1f, proj_f, 1536 * 8, 256, 128, 128, 128, 256);
    gemm(h_h0, Wih_h1b, b_h1b, proj_b, 1536 * 8, 256, 128, 128, 128, 256);
    lstm_scan_kernel<<<dim3(1536, 2), blk, 0, stream>>>(proj_f, proj_b, Whh_h1f, Whh_h1b,
                                                        l_hpu, h1_head, 8, 128);
    build_hs_kernel<<<dim3(96, 16), blk, 0, stream>>>(h1_head, l_hpu, knowledge_header, wenc_hs);
    build_hsob_kernel<<<dim3(96, 4), blk, 0, stream>>>(wenc_hs, wc, wn, hs_ob);

    // ---- attention ----
    gemm(wenc_n, Watt_w, Watt_b, attx, 96 * 512, 132, 140, 140, 140, 132);
    att_softmax_cn_kernel<<<dim3(96, 4), blk, 0, stream>>>(attx, hs_ob, wenc_n, l_n, c_n);

    // ---- vec / split out1 ----
    build_vec_kernel<<<dim3(96, 4), dim3(384), 0, stream>>>(c_n, hs_ob, Wc_w, Wc_b,
                                                            Whs_w, Whs_b, Wop_w, Wop_b,
                                                            wn, wo, vec);
    gemm(vec, out1_w, out1_b, vpart, 96 * 4, 128, 384, 384, 524, 128);
    gemm(wenc_n, out1_w + 384, nullptr, npart, 96 * 512, 128, 140, 140, 524, 128);

    // ---- final ----
    final_kernel<<<dim3(2, 96), blk, 0, stream>>>(vpart, npart, out2_w, out2_b, l_n, outp);
}

// Round 3
// 1749.801 us; speedup vs baseline: 1.1480x; 1.1017x over previous
//
#include <hip/hip_runtime.h>
#include <math.h>

#define NEGV -1e10f

typedef __bf16 bf16x8 __attribute__((ext_vector_type(8)));
typedef float f32x4 __attribute__((ext_vector_type(4)));

__device__ __forceinline__ float fast_sig(float x) {
    return 1.0f / (1.0f + __expf(-x));
}
__device__ __forceinline__ float fast_tanh(float x) {
    float ax = fabsf(x);
    float e = __expf(2.0f * ax);
    float t = 1.0f - 2.0f / (e + 1.0f);
    return copysignf(t, x);
}
__device__ __forceinline__ unsigned short f2bf(float x) {
    unsigned int b = __float_as_uint(x);
    b += 0x7fffu + ((b >> 16) & 1u);   // RNE
    return (unsigned short)(b >> 16);
}

// ---------------- GEMM: C[M,N] = A[M,K] @ B[N,K]^T (+bias[N]) ----------------
// perm!=0: store column col at permuted position (col&63)*4 + (col>>6)
// (gate-major [4][64] -> unit-major [64][4], for float4 proj reads in the scan).
__global__ __launch_bounds__(256) void gemm_bias_kernel(
    const float* __restrict__ A, const float* __restrict__ B,
    const float* __restrict__ bias, float* __restrict__ C,
    int M, int N, int K, int lda, int ldb, int ldc, int perm)
{
    __shared__ float As[16][68];
    __shared__ float Bs[16][68];
    const int tid = threadIdx.x;
    const int bm = blockIdx.y * 64;
    const int bn = blockIdx.x * 64;
    const int tx = tid & 15;
    const int ty = tid >> 4;
    const int lm = tid & 63;
    const int lk = (tid >> 6) << 2;   // 0,4,8,12
    float acc[4][4] = {};
    const int arow = bm + lm;
    const int brow = bn + lm;

    for (int k0 = 0; k0 < K; k0 += 16) {
        int k = k0 + lk;
        float4 av = make_float4(0.f, 0.f, 0.f, 0.f);
        float4 bv = make_float4(0.f, 0.f, 0.f, 0.f);
        if (arow < M) {
            if (k + 4 <= K) {
                av = *(const float4*)(A + (size_t)arow * lda + k);
            } else {
                float* p = (float*)&av;
                for (int i = 0; i < 4; i++) if (k + i < K) p[i] = A[(size_t)arow * lda + k + i];
            }
        }
        if (brow < N) {
            if (k + 4 <= K) {
                bv = *(const float4*)(B + (size_t)brow * ldb + k);
            } else {
                float* p = (float*)&bv;
                for (int i = 0; i < 4; i++) if (k + i < K) p[i] = B[(size_t)brow * ldb + k + i];
            }
        }
        As[lk + 0][lm] = av.x; As[lk + 1][lm] = av.y; As[lk + 2][lm] = av.z; As[lk + 3][lm] = av.w;
        Bs[lk + 0][lm] = bv.x; Bs[lk + 1][lm] = bv.y; Bs[lk + 2][lm] = bv.z; Bs[lk + 3][lm] = bv.w;
        __syncthreads();
        #pragma unroll
        for (int kk = 0; kk < 16; kk++) {
            float a[4], bb[4];
            #pragma unroll
            for (int i = 0; i < 4; i++) a[i] = As[kk][ty * 4 + i];
            #pragma unroll
            for (int j = 0; j < 4; j++) bb[j] = Bs[kk][tx * 4 + j];
            #pragma unroll
            for (int i = 0; i < 4; i++)
                #pragma unroll
                for (int j = 0; j < 4; j++)
                    acc[i][j] = fmaf(a[i], bb[j], acc[i][j]);
        }
        __syncthreads();
    }
    #pragma unroll
    for (int i = 0; i < 4; i++) {
        int row = bm + ty * 4 + i;
        if (row >= M) continue;
        #pragma unroll
        for (int j = 0; j < 4; j++) {
            int col = bn + tx * 4 + j;
            if (col < N) {
                int cout = perm ? ((col & 63) * 4 + (col >> 6)) : col;
                C[(size_t)row * ldc + cout] = acc[i][j] + (bias ? bias[col] : 0.f);
            }
        }
    }
}

// ------------- pre-pack Whh (8 matrices [256][64]) into MFMA B-frag order -------------
// frag[mat][tile(16)][chunk(2)][lane(64)][j(8)] = bf16( W[tile*16+(lane&15)][chunk*32+8*(lane>>4)+j] )
__global__ __launch_bounds__(256) void prepack_whh_kernel(
    const float* W0, const float* W1, const float* W2, const float* W3,
    const float* W4, const float* W5, const float* W6, const float* W7,
    unsigned short* frag)
{
    const float* Ws[8] = {W0, W1, W2, W3, W4, W5, W6, W7};
    const float* W = Ws[blockIdx.x];
    unsigned short* out = frag + (size_t)blockIdx.x * 16384;
    for (int r = 0; r < 8; r++) {
        int fl = threadIdx.x + 256 * r;            // 0..2047
        int tile = fl >> 7;
        int chunk = (fl >> 6) & 1;
        int lane = fl & 63;
        int row = tile * 16 + (lane & 15);
        int kb = chunk * 32 + 8 * (lane >> 4);
        #pragma unroll
        for (int j = 0; j < 8; j++)
            out[(size_t)fl * 8 + j] = f2bf(W[row * 64 + kb + j]);
    }
}

// ---------------- LSTM scan via MFMA: one block per (batch, direction) ----------------
// proj_*: [Bn][T][64 units][4 gates] float (permuted GEMM output).
// frag_*: pre-packed Whh B-fragments for this layer (16 tiles x 2 chunks x 64 lanes x 8).
// Wave w owns units 16w..16w+15 and uses tiles {4g+w} -> all 4 gates in-wave, no
// cross-wave exchange. h (64 x bf16) double-buffered in LDS; 1 barrier/step.
__global__ __launch_bounds__(256) void lstm_scan_mfma(
    const float* __restrict__ proj_f, const float* __restrict__ proj_b,
    const unsigned short* __restrict__ frag_f, const unsigned short* __restrict__ frag_b,
    const int* __restrict__ lengths,
    float* __restrict__ out, int T, int out_stride)
{
    const int b = blockIdx.x;
    const int dir = blockIdx.y;
    const float* proj = (dir ? proj_b : proj_f) + (size_t)b * T * 256;
    const unsigned short* frag = dir ? frag_b : frag_f;
    const int L = lengths[b];
    const int tid = threadIdx.x;
    const int wv = tid >> 6;
    const int ln = tid & 63;
    const int kg = ln >> 4;                 // k-group 0..3
    const int u = wv * 16 + (ln & 15);      // unit 0..63

    // weight fragments: 4 gates x 2 k-chunks, 16B each -> 32 VGPRs
    bf16x8 wf[4][2];
    #pragma unroll
    for (int g = 0; g < 4; g++)
        #pragma unroll
        for (int c = 0; c < 2; c++)
            wf[g][c] = *reinterpret_cast<const bf16x8*>(
                frag + (((size_t)(4 * g + wv) * 2 + c) * 64 + ln) * 8);

    __shared__ __align__(16) unsigned short hbuf[2][64];
    if (tid < 64) hbuf[0][tid] = 0;
    __syncthreads();

    float c_state = 0.f;
    float* outb = out + (size_t)b * T * out_stride + dir * 64;

    const int t0 = dir ? (L - 1) : 0;
    float4 p = *(const float4*)(proj + (size_t)t0 * 256 + u * 4);

    for (int s = 0; s < L; s++) {
        const int cur = s & 1;
        const int nxt = cur ^ 1;
        float4 pn = make_float4(0.f, 0.f, 0.f, 0.f);
        if (s + 1 < L) {
            const int tn = dir ? (L - 2 - s) : (s + 1);
            pn = *(const float4*)(proj + (size_t)tn * 256 + u * 4);
        }

        const char* hb = (const char*)hbuf[cur];
        bf16x8 a0 = *reinterpret_cast<const bf16x8*>(hb + kg * 16);        // h[0:32] slice
        bf16x8 a1 = *reinterpret_cast<const bf16x8*>(hb + 64 + kg * 16);   // h[32:64] slice

        f32x4 z = {0.f, 0.f, 0.f, 0.f};
        f32x4 acc0 = __builtin_amdgcn_mfma_f32_16x16x32_bf16(a0, wf[0][0], z, 0, 0, 0);
        f32x4 acc1 = __builtin_amdgcn_mfma_f32_16x16x32_bf16(a0, wf[1][0], z, 0, 0, 0);
        f32x4 acc2 = __builtin_amdgcn_mfma_f32_16x16x32_bf16(a0, wf[2][0], z, 0, 0, 0);
        f32x4 acc3 = __builtin_amdgcn_mfma_f32_16x16x32_bf16(a0, wf[3][0], z, 0, 0, 0);
        acc0 = __builtin_amdgcn_mfma_f32_16x16x32_bf16(a1, wf[0][1], acc0, 0, 0, 0);
        acc1 = __builtin_amdgcn_mfma_f32_16x16x32_bf16(a1, wf[1][1], acc1, 0, 0, 0);
        acc2 = __builtin_amdgcn_mfma_f32_16x16x32_bf16(a1, wf[2][1], acc2, 0, 0, 0);
        acc3 = __builtin_amdgcn_mfma_f32_16x16x32_bf16(a1, wf[3][1], acc3, 0, 0, 0);

        // C rows are all equal (A rows broadcast); col = lane&15 matches u.
        const float iv = fast_sig(acc0[0] + p.x);
        const float fv = fast_sig(acc1[0] + p.y);
        const float gv = fast_tanh(acc2[0] + p.z);
        const float ov = fast_sig(acc3[0] + p.w);
        c_state = fmaf(fv, c_state, iv * gv);
        const float hv = ov * fast_tanh(c_state);

        if (kg == 0) {
            const int t = dir ? (L - 1 - s) : s;
            outb[(size_t)t * out_stride + u] = hv;
            hbuf[nxt][u] = f2bf(hv);
        }
        __syncthreads();
        p = pn;
    }
    // zero-fill masked region t in [L, T)
    for (int idx = tid; idx < (T - L) * 64; idx += 256) {
        int t = L + (idx >> 6);
        outb[(size_t)t * out_stride + (idx & 63)] = 0.f;
    }
}

// ---------------- one-hot knowledge into wenc_n cols 128..139 ----------------
__global__ __launch_bounds__(256) void onehot_kernel(
    const int* __restrict__ knowledge, float* __restrict__ wenc_n)
{
    int idx = blockIdx.x * 256 + threadIdx.x;   // b*512 + t
    if (idx >= 96 * 512) return;
    int kn = knowledge[idx];
    float* row = wenc_n + (size_t)idx * 140 + 128;
    #pragma unroll
    for (int q = 0; q < 12; q++) row[q] = (q == kn) ? 1.f : 0.f;
}

// ---------------- header: pick last valid step + one-hot ----------------
__global__ __launch_bounds__(256) void build_hs_kernel(
    const float* __restrict__ h1_head, const int* __restrict__ l_hpu,
    const int* __restrict__ knowledge_header, float* __restrict__ wenc_hs)
{
    int b = blockIdx.x, u = blockIdx.y;
    int g = b * 16 + u;
    int tid = threadIdx.x;
    int L = l_hpu[g];
    if (tid < 128) {
        wenc_hs[(size_t)g * 132 + tid] = h1_head[((size_t)g * 8 + (L - 1)) * 128 + tid];
    } else if (tid < 132) {
        int kh = knowledge_header[g];
        wenc_hs[(size_t)g * 132 + tid] = ((tid - 128) == kh) ? 1.f : 0.f;
    }
}

__global__ __launch_bounds__(256) void build_hsob_kernel(
    const float* __restrict__ wenc_hs, const int* __restrict__ wc,
    const int* __restrict__ wn, float* __restrict__ hs_ob)
{
    int b = blockIdx.x, w = blockIdx.y;
    int tid = threadIdx.x;
    int col = (w < wn[b]) ? wc[b * 4 + w] : 0;
    if (tid < 132)
        hs_ob[((size_t)b * 4 + w)* 132 + tid] = wenc_hs[((size_t)b * 16 + col) * 132 + tid];
}

// ---------------- attention scores + softmax + context (per (b,w)) ----------------
__global__ __launch_bounds__(256) void att_softmax_cn_kernel(
    const float* __restrict__ attx, const float* __restrict__ hs_ob,
    const float* __restrict__ wenc_n, const int* __restrict__ l_n,
    float* __restrict__ c_n)
{
    int b = blockIdx.x, w = blockIdx.y;
    int tid = threadIdx.x;
    int L = l_n[b];
    __shared__ float q[132];
    __shared__ float sc[512];
    __shared__ float red[256];
    if (tid < 132) q[tid] = hs_ob[((size_t)b * 4 + w) * 132 + tid];
    __syncthreads();
    for (int t = tid; t < 512; t += 256) {
        float s = -1e30f;
        if (t < L) {
            const float* ax = attx + ((size_t)b * 512 + t) * 132;
            float s0 = 0.f, s1 = 0.f, s2 = 0.f, s3 = 0.f;
            #pragma unroll
            for (int d = 0; d < 132; d += 4) {
                s0 = fmaf(ax[d + 0], q[d + 0], s0);
                s1 = fmaf(ax[d + 1], q[d + 1], s1);
                s2 = fmaf(ax[d + 2], q[d + 2], s2);
                s3 = fmaf(ax[d + 3], q[d + 3], s3);
            }
            s = (s0 + s1) + (s2 + s3);
        }
        sc[t] = s;
    }
    __syncthreads();
    red[tid] = fmaxf(sc[tid], sc[tid + 256]);
    __syncthreads();
    for (int off = 128; off > 0; off >>= 1) {
        if (tid < off) red[tid] = fmaxf(red[tid], red[tid + off]);
        __syncthreads();
    }
    float m = red[0];
    __syncthreads();
    float ps = 0.f;
    for (int t = tid; t < 512; t += 256) {
        float e = (t < L) ? __expf(sc[t] - m) : 0.f;
        sc[t] = e;
        ps += e;
    }
    red[tid] = ps;
    __syncthreads();
    for (int off = 128; off > 0; off >>= 1) {
        if (tid < off) red[tid] += red[tid + off];
        __syncthreads();
    }
    float inv = 1.f / red[0];
    if (tid < 140) {
        float acc = 0.f;
        for (int t = 0; t < L; t++)
            acc = fmaf(sc[t], wenc_n[((size_t)b * 512 + t) * 140 + tid], acc);
        c_n[((size_t)b * 4 + w) * 140 + tid] = acc * inv;
    }
}

// ---------------- vec = [c_n@Wc.T+b | hs_ob@Whs.T+b | Wop[:,op]+b] ----------------
__global__ __launch_bounds__(384) void build_vec_kernel(
    const float* __restrict__ c_n, const float* __restrict__ hs_ob,
    const float* __restrict__ Wc_w, const float* __restrict__ Wc_b,
    const float* __restrict__ Whs_w, const float* __restrict__ Whs_b,
    const float* __restrict__ Wop_w, const float* __restrict__ Wop_b,
    const int* __restrict__ wn, const int* __restrict__ wo,
    float* __restrict__ vec)
{
    int b = blockIdx.x, w = blockIdx.y;
    int j = threadIdx.x;
    __shared__ float cn[140];
    __shared__ float hb[132];
    if (j < 140) cn[j] = c_n[((size_t)b * 4 + w) * 140 + j];
    else if (j < 272) hb[j - 140] = hs_ob[((size_t)b * 4 + w) * 132 + (j - 140)];
    __syncthreads();
    float acc;
    if (j < 128) {
        acc = Wc_b[j];
        const float* r = Wc_w + (size_t)j * 140;
        for (int d = 0; d < 140; d++) acc = fmaf(r[d], cn[d], acc);
    } else if (j < 256) {
        int jj = j - 128;
        acc = Whs_b[jj];
        const float* r = Whs_w + (size_t)jj * 132;
        for (int d = 0; d < 132; d++) acc = fmaf(r[d], hb[d], acc);
    } else {
        int jj = j - 256;
        int op = (w < wn[b]) ? wo[b * 4 + w] : 0;
        acc = Wop_b[jj] + Wop_w[jj * 4 + op];
    }
    vec[((size_t)b * 4 + w) * 384 + j] = acc;
}

// ---------------- final: out[b,w,t,:] = tanh(vpart+npart)@out2.T + b, masked ----------------
__global__ __launch_bounds__(256) void final_kernel(
    const float* __restrict__ vpart, const float* __restrict__ npart,
    const float* __restrict__ out2_w, const float* __restrict__ out2_b,
    const int* __restrict__ l_n, float* __restrict__ out)
{
    int b = blockIdx.y;
    int tid = threadIdx.x;
    int t = blockIdx.x * 256 + tid;
    __shared__ float vp[512];
    __shared__ float w2[256];
    w2[tid] = out2_w[tid];
    for (int i = tid; i < 512; i += 256) vp[i] = vpart[(size_t)b * 512 + i];
    __syncthreads();
    int L = l_n[b];
    float s[4][2];
    if (t < L) {
        float b0 = out2_b[0], b1 = out2_b[1];
        #pragma unroll
        for (int w = 0; w < 4; w++) { s[w][0] = b0; s[w][1] = b1; }
        const float4* np4 = (const float4*)(npart + ((size_t)b * 512 + t) * 128);
        for (int h4 = 0; h4 < 32; h4++) {
            float4 n = np4[h4];
            const float* nf = (const float*)&n;
            #pragma unroll
            for (int e = 0; e < 4; e++) {
                int h = h4 * 4 + e;
                float nv = nf[e];
                float w0 = w2[h], w1 = w2[128 + h];
                #pragma unroll
                for (int w = 0; w < 4; w++) {
                    float z = fast_tanh(vp[w * 128 + h] + nv);
                    s[w][0] = fmaf(z, w0, s[w][0]);
                    s[w][1] = fmaf(z, w1, s[w][1]);
                }
            }
        }
    } else {
        #pragma unroll
        for (int w = 0; w < 4; w++) { s[w][0] = NEGV; s[w][1] = NEGV; }
    }
    #pragma unroll
    for (int w = 0; w < 4; w++) {
        size_t o = (((size_t)b * 4 + w) * 512 + t) * 2;
        out[o + 0] = s[w][0];
        out[o + 1] = s[w][1];
    }
}

// ---------------------------------------------------------------------------
extern "C" void kernel_launch(void* const* d_in, const int* in_sizes, int n_in,
                              void* d_out, int out_size, void* d_ws, size_t ws_size,
                              hipStream_t stream)
{
    const float* wemb_n   = (const float*)d_in[0];
    const float* wemb_hpu = (const float*)d_in[1];
    const float* Wih_n0f = (const float*)d_in[2];
    const float* Whh_n0f = (const float*)d_in[3];
    const float* b_n0f   = (const float*)d_in[4];
    const float* Wih_n0b = (const float*)d_in[5];
    const float* Whh_n0b = (const float*)d_in[6];
    const float* b_n0b   = (const float*)d_in[7];
    const float* Wih_n1f = (const float*)d_in[8];
    const float* Whh_n1f = (const float*)d_in[9];
    const float* b_n1f   = (const float*)d_in[10];
    const float* Wih_n1b = (const float*)d_in[11];
    const float* Whh_n1b = (const float*)d_in[12];
    const float* b_n1b   = (const float*)d_in[13];
    const float* Wih_h0f = (const float*)d_in[14];
    const float* Whh_h0f = (const float*)d_in[15];
    const float* b_h0f   = (const float*)d_in[16];
    const float* Wih_h0b = (const float*)d_in[17];
    const float* Whh_h0b = (const float*)d_in[18];
    const float* b_h0b   = (const float*)d_in[19];
    const float* Wih_h1f = (const float*)d_in[20];
    const float* Whh_h1f = (const float*)d_in[21];
    const float* b_h1f   = (const float*)d_in[22];
    const float* Wih_h1b = (const float*)d_in[23];
    const float* Whh_h1b = (const float*)d_in[24];
    const float* b_h1b   = (const float*)d_in[25];
    const float* Watt_w  = (const float*)d_in[26];
    const float* Watt_b  = (const float*)d_in[27];
    const float* Wc_w    = (const float*)d_in[28];
    const float* Wc_b    = (const float*)d_in[29];
    const float* Whs_w   = (const float*)d_in[30];
    const float* Whs_b   = (const float*)d_in[31];
    const float* Wop_w   = (const float*)d_in[32];
    const float* Wop_b   = (const float*)d_in[33];
    const float* out1_w  = (const float*)d_in[34];
    const float* out1_b  = (const float*)d_in[35];
    const float* out2_w  = (const float*)d_in[36];
    const float* out2_b  = (const float*)d_in[37];
    const int* l_n   = (const int*)d_in[38];
    const int* l_hpu = (const int*)d_in[39];
    const int* wc    = (const int*)d_in[40];
    const int* wn    = (const int*)d_in[41];
    const int* wo    = (const int*)d_in[42];
    const int* knowledge        = (const int*)d_in[43];
    const int* knowledge_header = (const int*)d_in[44];

    float* ws = (float*)d_ws;
    // workspace layout (floats); proj region reused for attx/npart after header
    float* proj_f  = ws + 0;           // 12,582,912
    float* proj_b  = ws + 12582912;    // 12,582,912
    float* wenc0   = ws + 25165824;    // 6,291,456  (question L0 out; header h0 reuses)
    float* h_h0    = ws + 25165824;    // 1,572,864
    float* h1_head = ws + 26738688;    // 1,572,864
    float* wenc_n  = ws + 31457280;    // 6,881,280  [96,512,140]
    float* attx    = ws + 0;           // 6,488,064  (reuse proj area, after header done)
    float* npart   = ws + 6488064;     // 6,291,456  (reuse proj area)
    float* wenc_hs = ws + 38338560;    // 202,752
    float* hs_ob   = ws + 38541312;    // 50,688
    float* c_n     = ws + 38592000;    // 53,760
    float* vec     = ws + 38645760;    // 147,456
    float* vpart   = ws + 38793216;    // 49,152
    // weight fragments overlap c_n/vec/vpart region: frags are dead before
    // those are first written (attention phase starts after all scans).
    unsigned short* wfrag = (unsigned short*)(ws + 38592000);  // 8*16384 ushort = 256 KB
    float* outp    = (float*)d_out;

    dim3 blk(256);
    auto gemm = [&](const float* A, const float* B, const float* bias, float* C,
                    int M, int N, int K, int lda, int ldb, int ldc, int perm) {
        dim3 grid((N + 63) / 64, (M + 63) / 64);
        gemm_bias_kernel<<<grid, blk, 0, stream>>>(A, B, bias, C, M, N, K, lda, ldb, ldc, perm);
    };

    // ---- pre-pack all 8 Whh matrices into MFMA B-fragment order ----
    prepack_whh_kernel<<<dim3(8), blk, 0, stream>>>(
        Whh_n0f, Whh_n0b, Whh_n1f, Whh_n1b, Whh_h0f, Whh_h0b, Whh_h1f, Whh_h1b, wfrag);

    // ---- question encoder, layer 0 (input 512) ----
    gemm(wemb_n, Wih_n0f, b_n0f, proj_f, 96 * 512, 256, 512, 512, 512, 256, 1);
    gemm(wemb_n, Wih_n0b, b_n0b, proj_b, 96 * 512, 256, 512, 512, 512, 256, 1);
    lstm_scan_mfma<<<dim3(96, 2), blk, 0, stream>>>(proj_f, proj_b,
        wfrag + 0 * 16384, wfrag + 1 * 16384, l_n, wenc0, 512, 128);
    // ---- question encoder, layer 1 (input 128) ----
    gemm(wenc0, Wih_n1f, b_n1f, proj_f, 96 * 512, 256, 128, 128, 128, 256, 1);
    gemm(wenc0, Wih_n1b, b_n1b, proj_b, 96 * 512, 256, 128, 128, 128, 256, 1);
    lstm_scan_mfma<<<dim3(96, 2), blk, 0, stream>>>(proj_f, proj_b,
        wfrag + 2 * 16384, wfrag + 3 * 16384, l_n, wenc_n, 512, 140);
    onehot_kernel<<<dim3(192), blk, 0, stream>>>(knowledge, wenc_n);

    // ---- header encoder, layer 0 ----
    gemm(wemb_hpu, Wih_h0f, b_h0f, proj_f, 1536 * 8, 256, 512, 512, 512, 256, 1);
    gemm(wemb_hpu, Wih_h0b, b_h0b, proj_b, 1536 * 8, 256, 512, 512, 512, 256, 1);
    lstm_scan_mfma<<<dim3(1536, 2), blk, 0, stream>>>(proj_f, proj_b,
        wfrag + 4 * 16384, wfrag + 5 * 16384, l_hpu, h_h0, 8, 128);
    // ---- header encoder, layer 1 ----
    gemm(h_h0, Wih_h1f, b_h1f, proj_f, 1536 * 8, 256, 128, 128, 128, 256, 1);
    gemm(h_h0, Wih_h1b, b_h1b, proj_b, 1536 * 8, 256, 128, 128, 128, 256, 1);
    lstm_scan_mfma<<<dim3(1536, 2), blk, 0, stream>>>(proj_f, proj_b,
        wfrag + 6 * 16384, wfrag + 7 * 16384, l_hpu, h1_head, 8, 128);
    build_hs_kernel<<<dim3(96, 16), blk, 0, stream>>>(h1_head, l_hpu, knowledge_header, wenc_hs);
    build_hsob_kernel<<<dim3(96, 4), blk, 0, stream>>>(wenc_hs, wc, wn, hs_ob);

    // ---- attention ----
    gemm(wenc_n, Watt_w, Watt_b, attx, 96 * 512, 132, 140, 140, 140, 132, 0);
    att_softmax_cn_kernel<<<dim3(96, 4), blk, 0, stream>>>(attx, hs_ob, wenc_n, l_n, c_n);

    // ---- vec / split out1 ----
    build_vec_kernel<<<dim3(96, 4), dim3(384), 0, stream>>>(c_n, hs_ob, Wc_w, Wc_b,
                                                            Whs_w, Whs_b, Wop_w, Wop_b,
                                                            wn, wo, vec);
    gemm(vec, out1_w, out1_b, vpart, 96 * 4, 128, 384, 384, 524, 128, 0);
    gemm(wenc_n, out1_w + 384, nullptr, npart, 96 * 512, 128, 140, 140, 524, 128, 0);

    // ---- final ----
    final_kernel<<<dim3(2, 96), blk, 0, stream>>>(vpart, npart, out2_w, out2_b, l_n, outp);
}

// Round 4
// 937.775 us; speedup vs baseline: 2.1421x; 1.8659x over previous
//
#include <hip/hip_runtime.h>
#include <math.h>

#define NEGV -1e10f

typedef __bf16 bf16x8 __attribute__((ext_vector_type(8)));
typedef float f32x4 __attribute__((ext_vector_type(4)));
typedef unsigned short ushort;

__device__ __forceinline__ float fast_sig(float x) {
    return 1.0f / (1.0f + __expf(-x));
}
__device__ __forceinline__ float fast_tanh(float x) {
    float ax = fabsf(x);
    float e = __expf(2.0f * ax);
    float t = 1.0f - 2.0f / (e + 1.0f);
    return copysignf(t, x);
}
__device__ __forceinline__ ushort f2bf(float x) {
    unsigned int b = __float_as_uint(x);
    b += 0x7fffu + ((b >> 16) & 1u);   // RNE
    return (ushort)(b >> 16);
}
// raw barrier: wait LDS only, leave global loads in flight (no vmcnt drain)
__device__ __forceinline__ void lds_barrier() {
    asm volatile("s_waitcnt lgkmcnt(0)\n\ts_barrier" ::: "memory");
}
// async 16B global -> LDS (dest = wave-uniform base + lane*16)
__device__ __forceinline__ void async16(void* l, const void* g) {
    __builtin_amdgcn_global_load_lds(
        (const __attribute__((address_space(1))) void*)g,
        (__attribute__((address_space(3))) void*)l,
        16, 0, 0);
}

// ---------------- fp32 -> bf16 cast (n % 8 == 0) ----------------
__global__ __launch_bounds__(256) void cast_bf16_kernel(
    const float* __restrict__ in, ushort* __restrict__ out, int n)
{
    int i = (blockIdx.x * 256 + threadIdx.x) * 8;
    if (i >= n) return;
    float4 a = *(const float4*)(in + i);
    float4 b = *(const float4*)(in + i + 4);
    uint4 o;
    o.x = (unsigned)f2bf(a.x) | ((unsigned)f2bf(a.y) << 16);
    o.y = (unsigned)f2bf(a.z) | ((unsigned)f2bf(a.w) << 16);
    o.z = (unsigned)f2bf(b.x) | ((unsigned)f2bf(b.y) << 16);
    o.w = (unsigned)f2bf(b.z) | ((unsigned)f2bf(b.w) << 16);
    *(uint4*)(out + i) = o;
}

// ---------------- MFMA GEMM: C[M,256] = A[M,K]bf16 @ B[256,K]bf16^T + bias ----------------
// N fixed 256 (grid.x=2), K % 64 == 0, M % 128 == 0. Store col-permuted
// (gate-major n -> unit-major (n&63)*4+(n>>6)) for the scan's float4 reads.
// LDS swizzle (T2, both-sides): phys_byte(r, cb) = r*128 + (cb ^ ((r&7)<<4)).
__global__ __launch_bounds__(256) void gemm_mfma_kernel(
    const ushort* __restrict__ A, const ushort* __restrict__ B,
    const float* __restrict__ bias, float* __restrict__ C,
    int M, int K)
{
    __shared__ __align__(16) ushort ldsA[128 * 64];
    __shared__ __align__(16) ushort ldsB[128 * 64];
    const int tid = threadIdx.x;
    const int wv = tid >> 6, ln = tid & 63;
    const int bm = blockIdx.y * 128, bn = blockIdx.x * 128;
    const int r15 = ln & 15, r4 = ln >> 4;

    f32x4 acc[4][4] = {};

    for (int k0 = 0; k0 < K; k0 += 64) {
        #pragma unroll
        for (int c4 = 0; c4 < 4; c4++) {
            const int c = c4 * 4 + wv;            // 16 chunks of 1KB per tile
            const int s = c * 64 + ln;            // linear 16B slot
            const int rt = s >> 3;                // tile row
            const int ce = ((s & 7) ^ (rt & 7)) * 8;  // swizzled k-element offset
            async16(&ldsA[c * 512], A + (size_t)(bm + rt) * K + k0 + ce);
            async16(&ldsB[c * 512], B + (size_t)(bn + rt) * K + k0 + ce);
        }
        __syncthreads();   // drains vmcnt -> staged data visible
        const int mr = (wv >> 1) * 64, nc = (wv & 1) * 64;
        #pragma unroll
        for (int kk = 0; kk < 2; kk++) {
            bf16x8 af[4], bfr[4];
            #pragma unroll
            for (int m = 0; m < 4; m++) {
                const int r = mr + m * 16 + r15;
                const int off = r * 128 + ((kk * 64 + r4 * 16) ^ ((r & 7) << 4));
                af[m] = *(const bf16x8*)((const char*)ldsA + off);
            }
            #pragma unroll
            for (int n = 0; n < 4; n++) {
                const int r = nc + n * 16 + r15;
                const int off = r * 128 + ((kk * 64 + r4 * 16) ^ ((r & 7) << 4));
                bfr[n] = *(const bf16x8*)((const char*)ldsB + off);
            }
            #pragma unroll
            for (int m = 0; m < 4; m++)
                #pragma unroll
                for (int n = 0; n < 4; n++)
                    acc[m][n] = __builtin_amdgcn_mfma_f32_16x16x32_bf16(
                        af[m], bfr[n], acc[m][n], 0, 0, 0);
        }
        __syncthreads();
    }
    const int mr = bm + (wv >> 1) * 64, nc = bn + (wv & 1) * 64;
    #pragma unroll
    for (int m = 0; m < 4; m++) {
        #pragma unroll
        for (int n = 0; n < 4; n++) {
            const int col = nc + n * 16 + r15;
            const int cout = (col & 63) * 4 + (col >> 6);
            const float bs = bias[col];
            #pragma unroll
            for (int r = 0; r < 4; r++) {
                const int row = mr + m * 16 + r4 * 4 + r;
                C[(size_t)row * 256 + cout] = acc[m][n][r] + bs;
            }
        }
    }
}

// ---------------- SIMT GEMM (small-N tail ops): C = A @ B^T (+bias) ----------------
__global__ __launch_bounds__(256) void gemm_bias_kernel(
    const float* __restrict__ A, const float* __restrict__ B,
    const float* __restrict__ bias, float* __restrict__ C,
    int M, int N, int K, int lda, int ldb, int ldc)
{
    __shared__ float As[16][68];
    __shared__ float Bs[16][68];
    const int tid = threadIdx.x;
    const int bm = blockIdx.y * 64;
    const int bn = blockIdx.x * 64;
    const int tx = tid & 15;
    const int ty = tid >> 4;
    const int lm = tid & 63;
    const int lk = (tid >> 6) << 2;
    float acc[4][4] = {};
    const int arow = bm + lm;
    const int brow = bn + lm;

    for (int k0 = 0; k0 < K; k0 += 16) {
        int k = k0 + lk;
        float4 av = make_float4(0.f, 0.f, 0.f, 0.f);
        float4 bv = make_float4(0.f, 0.f, 0.f, 0.f);
        if (arow < M) {
            if (k + 4 <= K) {
                av = *(const float4*)(A + (size_t)arow * lda + k);
            } else {
                float* p = (float*)&av;
                for (int i = 0; i < 4; i++) if (k + i < K) p[i] = A[(size_t)arow * lda + k + i];
            }
        }
        if (brow < N) {
            if (k + 4 <= K) {
                bv = *(const float4*)(B + (size_t)brow * ldb + k);
            } else {
                float* p = (float*)&bv;
                for (int i = 0; i < 4; i++) if (k + i < K) p[i] = B[(size_t)brow * ldb + k + i];
            }
        }
        As[lk + 0][lm] = av.x; As[lk + 1][lm] = av.y; As[lk + 2][lm] = av.z; As[lk + 3][lm] = av.w;
        Bs[lk + 0][lm] = bv.x; Bs[lk + 1][lm] = bv.y; Bs[lk + 2][lm] = bv.z; Bs[lk + 3][lm] = bv.w;
        __syncthreads();
        #pragma unroll
        for (int kk = 0; kk < 16; kk++) {
            float a[4], bb[4];
            #pragma unroll
            for (int i = 0; i < 4; i++) a[i] = As[kk][ty * 4 + i];
            #pragma unroll
            for (int j = 0; j < 4; j++) bb[j] = Bs[kk][tx * 4 + j];
            #pragma unroll
            for (int i = 0; i < 4; i++)
                #pragma unroll
                for (int j = 0; j < 4; j++)
                    acc[i][j] = fmaf(a[i], bb[j], acc[i][j]);
        }
        __syncthreads();
    }
    #pragma unroll
    for (int i = 0; i < 4; i++) {
        int row = bm + ty * 4 + i;
        if (row >= M) continue;
        #pragma unroll
        for (int j = 0; j < 4; j++) {
            int col = bn + tx * 4 + j;
            if (col < N) C[(size_t)row * ldc + col] = acc[i][j] + (bias ? bias[col] : 0.f);
        }
    }
}

// ------------- pre-pack Whh (8 matrices [256][64]) into MFMA B-frag order -------------
__global__ __launch_bounds__(256) void prepack_whh_kernel(
    const float* W0, const float* W1, const float* W2, const float* W3,
    const float* W4, const float* W5, const float* W6, const float* W7,
    ushort* frag)
{
    const float* Ws[8] = {W0, W1, W2, W3, W4, W5, W6, W7};
    const float* W = Ws[blockIdx.x];
    ushort* out = frag + (size_t)blockIdx.x * 16384;
    for (int r = 0; r < 8; r++) {
        int fl = threadIdx.x + 256 * r;            // 0..2047
        int tile = fl >> 7;
        int chunk = (fl >> 6) & 1;
        int lane = fl & 63;
        int row = tile * 16 + (lane & 15);
        int kb = chunk * 32 + 8 * (lane >> 4);
        #pragma unroll
        for (int j = 0; j < 8; j++)
            out[(size_t)fl * 8 + j] = f2bf(W[row * 64 + kb + j]);
    }
}

// ---------------- LSTM scan via MFMA, raw-barrier + depth-3 prefetch ----------------
__global__ __launch_bounds__(256) void lstm_scan_mfma(
    const float* __restrict__ proj_f, const float* __restrict__ proj_b,
    const ushort* __restrict__ frag_f, const ushort* __restrict__ frag_b,
    const int* __restrict__ lengths,
    float* __restrict__ out, int T, int out_stride)
{
    const int b = blockIdx.x;
    const int dir = blockIdx.y;
    const float* proj = (dir ? proj_b : proj_f) + (size_t)b * T * 256;
    const ushort* frag = dir ? frag_b : frag_f;
    const int L = lengths[b];
    const int tid = threadIdx.x;
    const int wv = tid >> 6;
    const int ln = tid & 63;
    const int kg = ln >> 4;
    const int u = wv * 16 + (ln & 15);

    bf16x8 wf[4][2];
    #pragma unroll
    for (int g = 0; g < 4; g++)
        #pragma unroll
        for (int c = 0; c < 2; c++)
            wf[g][c] = *reinterpret_cast<const bf16x8*>(
                frag + (((size_t)(4 * g + wv) * 2 + c) * 64 + ln) * 8);

    __shared__ __align__(16) ushort hbuf[2][64];
    if (tid < 64) hbuf[0][tid] = 0;
    __syncthreads();

    float c_state = 0.f;
    float* outb = out + (size_t)b * T * out_stride + dir * 64;

    auto ldp = [&](int s) -> float4 {
        if (s < L) {
            const int t = dir ? (L - 1 - s) : s;
            return *(const float4*)(proj + (size_t)t * 256 + u * 4);
        }
        return make_float4(0.f, 0.f, 0.f, 0.f);
    };
    float4 pA = ldp(0), pB = ldp(1), pC = ldp(2);

    for (int s = 0; s < L; s++) {
        const int cur = s & 1;
        const int nxt = cur ^ 1;
        float4 pD = ldp(s + 3);    // stays in flight across the raw barrier

        const char* hb = (const char*)hbuf[cur];
        bf16x8 a0 = *reinterpret_cast<const bf16x8*>(hb + kg * 16);
        bf16x8 a1 = *reinterpret_cast<const bf16x8*>(hb + 64 + kg * 16);

        f32x4 z = {0.f, 0.f, 0.f, 0.f};
        f32x4 acc0 = __builtin_amdgcn_mfma_f32_16x16x32_bf16(a0, wf[0][0], z, 0, 0, 0);
        f32x4 acc1 = __builtin_amdgcn_mfma_f32_16x16x32_bf16(a0, wf[1][0], z, 0, 0, 0);
        f32x4 acc2 = __builtin_amdgcn_mfma_f32_16x16x32_bf16(a0, wf[2][0], z, 0, 0, 0);
        f32x4 acc3 = __builtin_amdgcn_mfma_f32_16x16x32_bf16(a0, wf[3][0], z, 0, 0, 0);
        acc0 = __builtin_amdgcn_mfma_f32_16x16x32_bf16(a1, wf[0][1], acc0, 0, 0, 0);
        acc1 = __builtin_amdgcn_mfma_f32_16x16x32_bf16(a1, wf[1][1], acc1, 0, 0, 0);
        acc2 = __builtin_amdgcn_mfma_f32_16x16x32_bf16(a1, wf[2][1], acc2, 0, 0, 0);
        acc3 = __builtin_amdgcn_mfma_f32_16x16x32_bf16(a1, wf[3][1], acc3, 0, 0, 0);

        const float iv = fast_sig(acc0[0] + pA.x);
        const float fv = fast_sig(acc1[0] + pA.y);
        const float gv = fast_tanh(acc2[0] + pA.z);
        const float ov = fast_sig(acc3[0] + pA.w);
        c_state = fmaf(fv, c_state, iv * gv);
        const float hv = ov * fast_tanh(c_state);

        if (kg == 0) {
            const int t = dir ? (L - 1 - s) : s;
            outb[(size_t)t * out_stride + u] = hv;
            hbuf[nxt][u] = f2bf(hv);
        }
        pA = pB; pB = pC; pC = pD;
        lds_barrier();   // lgkmcnt(0) + s_barrier only; no vmcnt drain
    }
    for (int idx = tid; idx < (T - L) * 64; idx += 256) {
        int t = L + (idx >> 6);
        outb[(size_t)t * out_stride + (idx & 63)] = 0.f;
    }
}

// ---------------- one-hot knowledge into wenc_n cols 128..139 ----------------
__global__ __launch_bounds__(256) void onehot_kernel(
    const int* __restrict__ knowledge, float* __restrict__ wenc_n)
{
    int idx = blockIdx.x * 256 + threadIdx.x;
    if (idx >= 96 * 512) return;
    int kn = knowledge[idx];
    float* row = wenc_n + (size_t)idx * 140 + 128;
    #pragma unroll
    for (int q = 0; q < 12; q++) row[q] = (q == kn) ? 1.f : 0.f;
}

// ---------------- header: pick last valid step + one-hot ----------------
__global__ __launch_bounds__(256) void build_hs_kernel(
    const float* __restrict__ h1_head, const int* __restrict__ l_hpu,
    const int* __restrict__ knowledge_header, float* __restrict__ wenc_hs)
{
    int b = blockIdx.x, u = blockIdx.y;
    int g = b * 16 + u;
    int tid = threadIdx.x;
    int L = l_hpu[g];
    if (tid < 128) {
        wenc_hs[(size_t)g * 132 + tid] = h1_head[((size_t)g * 8 + (L - 1)) * 128 + tid];
    } else if (tid < 132) {
        int kh = knowledge_header[g];
        wenc_hs[(size_t)g * 132 + tid] = ((tid - 128) == kh) ? 1.f : 0.f;
    }
}

__global__ __launch_bounds__(256) void build_hsob_kernel(
    const float* __restrict__ wenc_hs, const int* __restrict__ wc,
    const int* __restrict__ wn, float* __restrict__ hs_ob)
{
    int b = blockIdx.x, w = blockIdx.y;
    int tid = threadIdx.x;
    int col = (w < wn[b]) ? wc[b * 4 + w] : 0;
    if (tid < 132)
        hs_ob[((size_t)b * 4 + w)* 132 + tid] = wenc_hs[((size_t)b * 16 + col) * 132 + tid];
}

// ---------------- attention scores + softmax + context (per (b,w)) ----------------
__global__ __launch_bounds__(256) void att_softmax_cn_kernel(
    const float* __restrict__ attx, const float* __restrict__ hs_ob,
    const float* __restrict__ wenc_n, const int* __restrict__ l_n,
    float* __restrict__ c_n)
{
    int b = blockIdx.x, w = blockIdx.y;
    int tid = threadIdx.x;
    int L = l_n[b];
    __shared__ float q[132];
    __shared__ float sc[512];
    __shared__ float red[256];
    if (tid < 132) q[tid] = hs_ob[((size_t)b * 4 + w) * 132 + tid];
    __syncthreads();
    for (int t = tid; t < 512; t += 256) {
        float s = -1e30f;
        if (t < L) {
            const float* ax = attx + ((size_t)b * 512 + t) * 132;
            float s0 = 0.f, s1 = 0.f, s2 = 0.f, s3 = 0.f;
            #pragma unroll
            for (int d = 0; d < 132; d += 4) {
                s0 = fmaf(ax[d + 0], q[d + 0], s0);
                s1 = fmaf(ax[d + 1], q[d + 1], s1);
                s2 = fmaf(ax[d + 2], q[d + 2], s2);
                s3 = fmaf(ax[d + 3], q[d + 3], s3);
            }
            s = (s0 + s1) + (s2 + s3);
        }
        sc[t] = s;
    }
    __syncthreads();
    red[tid] = fmaxf(sc[tid], sc[tid + 256]);
    __syncthreads();
    for (int off = 128; off > 0; off >>= 1) {
        if (tid < off) red[tid] = fmaxf(red[tid], red[tid + off]);
        __syncthreads();
    }
    float m = red[0];
    __syncthreads();
    float ps = 0.f;
    for (int t = tid; t < 512; t += 256) {
        float e = (t < L) ? __expf(sc[t] - m) : 0.f;
        sc[t] = e;
        ps += e;
    }
    red[tid] = ps;
    __syncthreads();
    for (int off = 128; off > 0; off >>= 1) {
        if (tid < off) red[tid] += red[tid + off];
        __syncthreads();
    }
    float inv = 1.f / red[0];
    if (tid < 140) {
        float acc = 0.f;
        for (int t = 0; t < L; t++)
            acc = fmaf(sc[t], wenc_n[((size_t)b * 512 + t) * 140 + tid], acc);
        c_n[((size_t)b * 4 + w) * 140 + tid] = acc * inv;
    }
}

// ---------------- vec = [c_n@Wc.T+b | hs_ob@Whs.T+b | Wop[:,op]+b] ----------------
__global__ __launch_bounds__(384) void build_vec_kernel(
    const float* __restrict__ c_n, const float* __restrict__ hs_ob,
    const float* __restrict__ Wc_w, const float* __restrict__ Wc_b,
    const float* __restrict__ Whs_w, const float* __restrict__ Whs_b,
    const float* __restrict__ Wop_w, const float* __restrict__ Wop_b,
    const int* __restrict__ wn, const int* __restrict__ wo,
    float* __restrict__ vec)
{
    int b = blockIdx.x, w = blockIdx.y;
    int j = threadIdx.x;
    __shared__ float cn[140];
    __shared__ float hb[132];
    if (j < 140) cn[j] = c_n[((size_t)b * 4 + w) * 140 + j];
    else if (j < 272) hb[j - 140] = hs_ob[((size_t)b * 4 + w) * 132 + (j - 140)];
    __syncthreads();
    float acc;
    if (j < 128) {
        acc = Wc_b[j];
        const float* r = Wc_w + (size_t)j * 140;
        for (int d = 0; d < 140; d++) acc = fmaf(r[d], cn[d], acc);
    } else if (j < 256) {
        int jj = j - 128;
        acc = Whs_b[jj];
        const float* r = Whs_w + (size_t)jj * 132;
        for (int d = 0; d < 132; d++) acc = fmaf(r[d], hb[d], acc);
    } else {
        int jj = j - 256;
        int op = (w < wn[b]) ? wo[b * 4 + w] : 0;
        acc = Wop_b[jj] + Wop_w[jj * 4 + op];
    }
    vec[((size_t)b * 4 + w) * 384 + j] = acc;
}

// ---------------- final: out[b,w,t,:] = tanh(vpart+npart)@out2.T + b, masked ----------------
__global__ __launch_bounds__(256) void final_kernel(
    const float* __restrict__ vpart, const float* __restrict__ npart,
    const float* __restrict__ out2_w, const float* __restrict__ out2_b,
    const int* __restrict__ l_n, float* __restrict__ out)
{
    int b = blockIdx.y;
    int tid = threadIdx.x;
    int t = blockIdx.x * 256 + tid;
    __shared__ float vp[512];
    __shared__ float w2[256];
    w2[tid] = out2_w[tid];
    for (int i = tid; i < 512; i += 256) vp[i] = vpart[(size_t)b * 512 + i];
    __syncthreads();
    int L = l_n[b];
    float s[4][2];
    if (t < L) {
        float b0 = out2_b[0], b1 = out2_b[1];
        #pragma unroll
        for (int w = 0; w < 4; w++) { s[w][0] = b0; s[w][1] = b1; }
        const float4* np4 = (const float4*)(npart + ((size_t)b * 512 + t) * 128);
        for (int h4 = 0; h4 < 32; h4++) {
            float4 n = np4[h4];
            const float* nf = (const float*)&n;
            #pragma unroll
            for (int e = 0; e < 4; e++) {
                int h = h4 * 4 + e;
                float nv = nf[e];
                float w0 = w2[h], w1 = w2[128 + h];
                #pragma unroll
                for (int w = 0; w < 4; w++) {
                    float z = fast_tanh(vp[w * 128 + h] + nv);
                    s[w][0] = fmaf(z, w0, s[w][0]);
                    s[w][1] = fmaf(z, w1, s[w][1]);
                }
            }
        }
    } else {
        #pragma unroll
        for (int w = 0; w < 4; w++) { s[w][0] = NEGV; s[w][1] = NEGV; }
    }
    #pragma unroll
    for (int w = 0; w < 4; w++) {
        size_t o = (((size_t)b * 4 + w) * 512 + t) * 2;
        out[o + 0] = s[w][0];
        out[o + 1] = s[w][1];
    }
}

// ---------------------------------------------------------------------------
extern "C" void kernel_launch(void* const* d_in, const int* in_sizes, int n_in,
                              void* d_out, int out_size, void* d_ws, size_t ws_size,
                              hipStream_t stream)
{
    const float* wemb_n   = (const float*)d_in[0];
    const float* wemb_hpu = (const float*)d_in[1];
    const float* Wih_n0f = (const float*)d_in[2];
    const float* Whh_n0f = (const float*)d_in[3];
    const float* b_n0f   = (const float*)d_in[4];
    const float* Wih_n0b = (const float*)d_in[5];
    const float* Whh_n0b = (const float*)d_in[6];
    const float* b_n0b   = (const float*)d_in[7];
    const float* Wih_n1f = (const float*)d_in[8];
    const float* Whh_n1f = (const float*)d_in[9];
    const float* b_n1f   = (const float*)d_in[10];
    const float* Wih_n1b = (const float*)d_in[11];
    const float* Whh_n1b = (const float*)d_in[12];
    const float* b_n1b   = (const float*)d_in[13];
    const float* Wih_h0f = (const float*)d_in[14];
    const float* Whh_h0f = (const float*)d_in[15];
    const float* b_h0f   = (const float*)d_in[16];
    const float* Wih_h0b = (const float*)d_in[17];
    const float* Whh_h0b = (const float*)d_in[18];
    const float* b_h0b   = (const float*)d_in[19];
    const float* Wih_h1f = (const float*)d_in[20];
    const float* Whh_h1f = (const float*)d_in[21];
    const float* b_h1f   = (const float*)d_in[22];
    const float* Wih_h1b = (const float*)d_in[23];
    const float* Whh_h1b = (const float*)d_in[24];
    const float* b_h1b   = (const float*)d_in[25];
    const float* Watt_w  = (const float*)d_in[26];
    const float* Watt_b  = (const float*)d_in[27];
    const float* Wc_w    = (const float*)d_in[28];
    const float* Wc_b    = (const float*)d_in[29];
    const float* Whs_w   = (const float*)d_in[30];
    const float* Whs_b   = (const float*)d_in[31];
    const float* Wop_w   = (const float*)d_in[32];
    const float* Wop_b   = (const float*)d_in[33];
    const float* out1_w  = (const float*)d_in[34];
    const float* out1_b  = (const float*)d_in[35];
    const float* out2_w  = (const float*)d_in[36];
    const float* out2_b  = (const float*)d_in[37];
    const int* l_n   = (const int*)d_in[38];
    const int* l_hpu = (const int*)d_in[39];
    const int* wc    = (const int*)d_in[40];
    const int* wn    = (const int*)d_in[41];
    const int* wo    = (const int*)d_in[42];
    const int* knowledge        = (const int*)d_in[43];
    const int* knowledge_header = (const int*)d_in[44];

    float* ws = (float*)d_ws;
    // fp32 regions (same map as R3)
    float* proj_f  = ws + 0;           // [0, 12582912)
    float* proj_b  = ws + 12582912;    // [12582912, 25165824)
    float* wenc0   = ws + 25165824;    // [25165824, 31457280)
    float* h_h0    = ws + 25165824;    // [25165824, 26738688)
    float* h1_head = ws + 26738688;    // [26738688, 28311552)
    float* wenc_n  = ws + 31457280;    // [31457280, 38338560)
    float* attx    = ws + 0;           // reuse proj area after header phase
    float* npart   = ws + 6488064;
    float* wenc_hs = ws + 38338560;    // [38338560, 38541312)
    float* hs_ob   = ws + 38541312;
    float* c_n     = ws + 38592000;
    float* vec     = ws + 38645760;
    float* vpart   = ws + 38793216;    // ends 38842368
    // bf16 aliases (lifetime-disjoint with the fp32 tenants):
    ushort* AbfQ0 = (ushort*)(ws + 25165824);  // wemb_n bf16 (dead before wenc0/wenc_n written)
    ushort* AbfQ1 = (ushort*)(ws + 31457280);  // wenc0 bf16 (dead before wenc_n written)
    ushort* AbfH0 = (ushort*)(ws + 25165824);  // wemb_hpu bf16 (wenc0 dead by header phase)
    ushort* AbfH1 = (ushort*)(ws + 28311552);  // h_h0 bf16 (gap region)
    ushort* Wbf   = (ushort*)(ws + 38338560);  // per-layer Wih bf16 (dead before wenc_hs)
    ushort* wfrag = (ushort*)(ws + 38592000);  // Whh frags (dead before c_n/vec written)
    float* outp    = (float*)d_out;

    dim3 blk(256);
    auto cast = [&](const float* in, ushort* out, int n) {
        cast_bf16_kernel<<<dim3(n / 2048), blk, 0, stream>>>(in, out, n);
    };
    auto mgemm = [&](const ushort* A, const ushort* B, const float* bias, float* C,
                     int M, int K) {
        gemm_mfma_kernel<<<dim3(2, M / 128), blk, 0, stream>>>(A, B, bias, C, M, K);
    };
    auto sgemm = [&](const float* A, const float* B, const float* bias, float* C,
                     int M, int N, int K, int lda, int ldb, int ldc) {
        dim3 grid((N + 63) / 64, (M + 63) / 64);
        gemm_bias_kernel<<<grid, blk, 0, stream>>>(A, B, bias, C, M, N, K, lda, ldb, ldc);
    };

    prepack_whh_kernel<<<dim3(8), blk, 0, stream>>>(
        Whh_n0f, Whh_n0b, Whh_n1f, Whh_n1b, Whh_h0f, Whh_h0b, Whh_h1f, Whh_h1b, wfrag);

    // ---- question encoder, layer 0 (K=512) ----
    cast(wemb_n, AbfQ0, 96 * 512 * 512);
    cast(Wih_n0f, Wbf, 256 * 512);
    cast(Wih_n0b, Wbf + 256 * 512, 256 * 512);
    mgemm(AbfQ0, Wbf, b_n0f, proj_f, 96 * 512, 512);
    mgemm(AbfQ0, Wbf + 256 * 512, b_n0b, proj_b, 96 * 512, 512);
    lstm_scan_mfma<<<dim3(96, 2), blk, 0, stream>>>(proj_f, proj_b,
        wfrag + 0 * 16384, wfrag + 1 * 16384, l_n, wenc0, 512, 128);

    // ---- question encoder, layer 1 (K=128) ----
    cast(wenc0, AbfQ1, 96 * 512 * 128);
    cast(Wih_n1f, Wbf, 256 * 128);
    cast(Wih_n1b, Wbf + 256 * 128, 256 * 128);
    mgemm(AbfQ1, Wbf, b_n1f, proj_f, 96 * 512, 128);
    mgemm(AbfQ1, Wbf + 256 * 128, b_n1b, proj_b, 96 * 512, 128);
    lstm_scan_mfma<<<dim3(96, 2), blk, 0, stream>>>(proj_f, proj_b,
        wfrag + 2 * 16384, wfrag + 3 * 16384, l_n, wenc_n, 512, 140);
    onehot_kernel<<<dim3(192), blk, 0, stream>>>(knowledge, wenc_n);

    // ---- header encoder, layer 0 (K=512) ----
    cast(wemb_hpu, AbfH0, 1536 * 8 * 512);
    cast(Wih_h0f, Wbf, 256 * 512);
    cast(Wih_h0b, Wbf + 256 * 512, 256 * 512);
    mgemm(AbfH0, Wbf, b_h0f, proj_f, 1536 * 8, 512);
    mgemm(AbfH0, Wbf + 256 * 512, b_h0b, proj_b, 1536 * 8, 512);
    lstm_scan_mfma<<<dim3(1536, 2), blk, 0, stream>>>(proj_f, proj_b,
        wfrag + 4 * 16384, wfrag + 5 * 16384, l_hpu, h_h0, 8, 128);

    // ---- header encoder, layer 1 (K=128) ----
    cast(h_h0, AbfH1, 1536 * 8 * 128);
    cast(Wih_h1f, Wbf, 256 * 128);
    cast(Wih_h1b, Wbf + 256 * 128, 256 * 128);
    mgemm(AbfH1, Wbf, b_h1f, proj_f, 1536 * 8, 128);
    mgemm(AbfH1, Wbf + 256 * 128, b_h1b, proj_b, 1536 * 8, 128);
    lstm_scan_mfma<<<dim3(1536, 2), blk, 0, stream>>>(proj_f, proj_b,
        wfrag + 6 * 16384, wfrag + 7 * 16384, l_hpu, h1_head, 8, 128);
    build_hs_kernel<<<dim3(96, 16), blk, 0, stream>>>(h1_head, l_hpu, knowledge_header, wenc_hs);
    build_hsob_kernel<<<dim3(96, 4), blk, 0, stream>>>(wenc_hs, wc, wn, hs_ob);

    // ---- attention ----
    sgemm(wenc_n, Watt_w, Watt_b, attx, 96 * 512, 132, 140, 140, 140, 132);
    att_softmax_cn_kernel<<<dim3(96, 4), blk, 0, stream>>>(attx, hs_ob, wenc_n, l_n, c_n);

    // ---- vec / split out1 ----
    build_vec_kernel<<<dim3(96, 4), dim3(384), 0, stream>>>(c_n, hs_ob, Wc_w, Wc_b,
                                                            Whs_w, Whs_b, Wop_w, Wop_b,
                                                            wn, wo, vec);
    sgemm(vec, out1_w, out1_b, vpart, 96 * 4, 128, 384, 384, 524, 128);
    sgemm(wenc_n, out1_w + 384, nullptr, npart, 96 * 512, 128, 140, 140, 524, 128);

    // ---- final ----
    final_kernel<<<dim3(2, 96), blk, 0, stream>>>(vpart, npart, out2_w, out2_b, l_n, outp);
}